// Round 11
// baseline (18475.670 us; speedup 1.0000x reference)
//
#include <hip/hip_runtime.h>
#include <hip/hip_bf16.h>
#include <math.h>

typedef unsigned short u16;
typedef unsigned int   u32;
typedef unsigned long long u64;
typedef __attribute__((ext_vector_type(8))) short short8;
typedef __attribute__((ext_vector_type(4))) float float4v;

#define BB 64
#define SS 512

// bf16 helpers (RNE)
__device__ __forceinline__ u16 f2b(float f) {
    u32 x = __float_as_uint(f);
    u32 r = (x + 0x7fffu + ((x >> 16) & 1u)) >> 16;
    return (u16)r;
}
__device__ __forceinline__ float b2f(u32 lo16) { return __uint_as_float(lo16 << 16); }
__device__ __forceinline__ float b2fh(u32 v)   { return __uint_as_float(v & 0xffff0000u); }

// ---------------------------------------------------------------------------
__global__ __launch_bounds__(256) void zero_kernel(float* __restrict__ p, int n) {
    int i = blockIdx.x * 256 + threadIdx.x;
    if (i < n) p[i] = 0.f;
}

// ---------------------------------------------------------------------------
__global__ __launch_bounds__(256) void pe_kernel(float* __restrict__ pe) {
    int s = blockIdx.x, j = threadIdx.x;
    float ang = (float)s * powf(10000.0f, -(2.0f * (float)j) / 512.0f);
    pe[s * 512 + 2 * j]     = sinf(ang);
    pe[s * 512 + 2 * j + 1] = cosf(ang);
}

// ---------------------------------------------------------------------------
// fp32 [R][C] -> bf16 [C][R]
// ---------------------------------------------------------------------------
__global__ __launch_bounds__(256) void transp_w(const float* __restrict__ in,
                                                u16* __restrict__ out, int R, int C) {
    __shared__ float t[64][65];
    int r0 = blockIdx.x * 64, c0 = blockIdx.y * 64;
    int tid = threadIdx.x;
    int lr = tid >> 4, lc4 = (tid & 15) * 4;
#pragma unroll
    for (int i = 0; i < 4; i++) {
        int r = lr + i * 16;
        float4 v = *(const float4*)(in + (long)(r0 + r) * C + c0 + lc4);
        t[r][lc4] = v.x; t[r][lc4 + 1] = v.y; t[r][lc4 + 2] = v.z; t[r][lc4 + 3] = v.w;
    }
    __syncthreads();
#pragma unroll
    for (int i = 0; i < 4; i++) {
        int c = lr + i * 16;
        u32 lo = (u32)f2b(t[lc4][c])     | ((u32)f2b(t[lc4 + 1][c]) << 16);
        u32 hi = (u32)f2b(t[lc4 + 2][c]) | ((u32)f2b(t[lc4 + 3][c]) << 16);
        uint2 pk; pk.x = lo; pk.y = hi;
        *(uint2*)(out + (long)(c0 + c) * R + r0 + lc4) = pk;
    }
}

// ---------------------------------------------------------------------------
__global__ __launch_bounds__(256) void cvt_bf16(const float* __restrict__ in,
                                                u16* __restrict__ out, long n) {
    long i = (long)blockIdx.x * 256 + threadIdx.x;
    if (i < n) out[i] = f2b(in[i]);
}

// ---------------------------------------------------------------------------
// Wh [2][1536][512] fp32 -> WT4 [2][128][1536][4] fp32  (k-blocked transpose)
// ---------------------------------------------------------------------------
__global__ __launch_bounds__(256) void wh_transp(const float* __restrict__ Wh,
                                                 float* __restrict__ WT4) {
    long i = (long)blockIdx.x * 256 + threadIdx.x;    // < 2*786432
    if (i >= 2L * 786432) return;
    long l = i / 786432;
    long r = i % 786432;
    int k4 = (int)(r / 6144);
    int rem = (int)(r % 6144);
    int j = rem >> 2, kk = rem & 3;
    WT4[i] = Wh[l * 786432 + (long)j * 512 + k4 * 4 + kk];
}

// ---------------------------------------------------------------------------
// bf16 [nb][R][C(ldin)] -> out[b][c][r] with element strides
// ---------------------------------------------------------------------------
__global__ __launch_bounds__(256) void transp_b(const u16* __restrict__ in,
                                                u16* __restrict__ out,
                                                int R, int C, int ldin,
                                                long sbin, long sb, long sc) {
    __shared__ u32 t[64][65];
    int bz = blockIdx.z;
    in += (long)bz * sbin;
    int r0 = blockIdx.x * 64, c0 = blockIdx.y * 64;
    int tid = threadIdx.x;
    int lr = tid >> 4, lc4 = (tid & 15) * 4;
#pragma unroll
    for (int i = 0; i < 4; i++) {
        int r = lr + i * 16;
        uint2 v = *(const uint2*)(in + (long)(r0 + r) * ldin + c0 + lc4);
        t[r][lc4] = v.x & 0xffffu; t[r][lc4 + 1] = v.x >> 16;
        t[r][lc4 + 2] = v.y & 0xffffu; t[r][lc4 + 3] = v.y >> 16;
    }
    __syncthreads();
#pragma unroll
    for (int i = 0; i < 4; i++) {
        int c = lr + i * 16;
        uint2 pk;
        pk.x = t[lc4][c] | (t[lc4 + 1][c] << 16);
        pk.y = t[lc4 + 2][c] | (t[lc4 + 3][c] << 16);
        *(uint2*)(out + (long)bz * sb + (long)(c0 + c) * sc + r0 + lc4) = pk;
    }
}

// ---------------------------------------------------------------------------
__global__ __launch_bounds__(256) void embed_kernel(
    const int* __restrict__ cate, const float* __restrict__ cont,
    const float* __restrict__ emb, const float* __restrict__ Wc,
    const float* __restrict__ bc, u16* __restrict__ xc, int gbase)
{
    long bs = (long)gbase + blockIdx.x;
    long r  = blockIdx.x;
    __shared__ float cf[6];
    if (threadIdx.x < 6) cf[threadIdx.x] = cont[bs * 6 + threadIdx.x];
    __syncthreads();
    for (int h = threadIdx.x; h < 1024; h += 256) {
        float v;
        if (h < 512) {
            int c = h >> 7, e = h & 127;
            int idx = cate[bs * 4 + c];
            v = emb[((long)c * 1000 + idx) * 128 + e];
        } else {
            int hh = h - 512;
            v = bc[hh];
#pragma unroll
            for (int f = 0; f < 6; f++) v += cf[f] * Wc[f * 512 + hh];
        }
        xc[r * 1024 + h] = f2b(v);
    }
}

// ---------------------------------------------------------------------------
// bf16 MFMA NT GEMM (validated: absmax 0.0)
// ---------------------------------------------------------------------------
__global__ __launch_bounds__(256) void gemm_nt(
    const u16* __restrict__ A, const u16* __restrict__ B, void* __restrict__ Cv,
    int K, int lda, int ldb, int ldc,
    long sA, long sB, long sC,
    const float* __restrict__ bias, const float* __restrict__ pe,
    float alpha, int outBf16)
{
    __shared__ u16 As[128][40];
    __shared__ u16 Bs[128][40];

    A += (long)blockIdx.z * sA;
    B += (long)blockIdx.z * sB;
    int m0 = blockIdx.y * 128, n0 = blockIdx.x * 128;
    int tid = threadIdx.x;
    int lane = tid & 63, wid = tid >> 6;
    int wm = (wid >> 1) * 64, wn = (wid & 1) * 64;
    int mrow = lane & 15, q8 = (lane >> 4) * 8;

    float4v acc[4][4];
#pragma unroll
    for (int i = 0; i < 4; i++)
#pragma unroll
        for (int j = 0; j < 4; j++) { float4v z = {0.f, 0.f, 0.f, 0.f}; acc[i][j] = z; }

    for (int k0 = 0; k0 < K; k0 += 32) {
        {
            int r = tid >> 2, sg = tid & 3;
            *(short8*)&As[r][sg * 8] = *(const short8*)(A + (long)(m0 + r) * lda + k0 + sg * 8);
            *(short8*)&Bs[r][sg * 8] = *(const short8*)(B + (long)(n0 + r) * ldb + k0 + sg * 8);
            r = (tid + 256) >> 2;
            *(short8*)&As[r][sg * 8] = *(const short8*)(A + (long)(m0 + r) * lda + k0 + sg * 8);
            *(short8*)&Bs[r][sg * 8] = *(const short8*)(B + (long)(n0 + r) * ldb + k0 + sg * 8);
        }
        __syncthreads();
        short8 af[4], bfr[4];
#pragma unroll
        for (int t = 0; t < 4; t++) {
            af[t]  = *(const short8*)&As[wm + t * 16 + mrow][q8];
            bfr[t] = *(const short8*)&Bs[wn + t * 16 + mrow][q8];
        }
#pragma unroll
        for (int i = 0; i < 4; i++)
#pragma unroll
            for (int j = 0; j < 4; j++)
                acc[i][j] = __builtin_amdgcn_mfma_f32_16x16x32_bf16(af[i], bfr[j], acc[i][j], 0, 0, 0);
        __syncthreads();
    }

    int col = lane & 15, quad = lane >> 4;
    u16*  Cb = (u16*)Cv  + (outBf16 ? (long)blockIdx.z * sC : 0);
    float* Cf = (float*)Cv + (outBf16 ? 0 : (long)blockIdx.z * sC);
#pragma unroll
    for (int i = 0; i < 4; i++)
#pragma unroll
        for (int j = 0; j < 4; j++) {
#pragma unroll
            for (int rr = 0; rr < 4; rr++) {
                int gm = m0 + wm + i * 16 + quad * 4 + rr;
                int gn = n0 + wn + j * 16 + col;
                float v = acc[i][j][rr] * alpha;
                if (bias) v += bias[gn];
                if (pe)   v += pe[(long)(gm & 511) * 512 + gn];
                if (outBf16) Cb[(long)gm * ldc + gn] = f2b(v);
                else         Cf[(long)gm * ldc + gn] = v;
            }
        }
}

// ---------------------------------------------------------------------------
// Softmax over QUERY axis fp32 -> bf16
// ---------------------------------------------------------------------------
__global__ __launch_bounds__(64) void softmax_q(const float* __restrict__ S,
                                                u16* __restrict__ P) {
    int b = blockIdx.x;
    int k = blockIdx.y * 64 + threadIdx.x;
    const float* p = S + (long)b * 262144 + k;
    u16* o = P + (long)b * 262144 + k;
    float m = -1e30f;
    for (int q = 0; q < 512; q++) m = fmaxf(m, p[(long)q * 512]);
    float sum = 0.f;
    for (int q = 0; q < 512; q++) sum += expf(p[(long)q * 512] - m);
    float inv = 1.f / sum;
    for (int q = 0; q < 512; q++) o[(long)q * 512] = f2b(expf(p[(long)q * 512] - m) * inv);
}

// ---------------------------------------------------------------------------
// Unit-split cooperative GRU — R8's EXACT validated work partition and math
// (hl[2][512] batch-major h, q=tid>>6 k-quarters, psum[4][3][2][64], same
// accumulation order, same tagged-atomic gather/exchange). ONE minimal change
// vs R8: the 96 loop-invariant float4 weight loads are hoisted into registers
// before the step loop (identical addresses/values -> bit-identical results).
// Grid 256 = 32 batch-pairs x 8 unit-slices, 1 block/CU.
// ---------------------------------------------------------------------------
__global__ __launch_bounds__(256, 1) void gru_ex(
    const float* __restrict__ gi,     // [128][64][1536] fp32 (includes bi)
    const float* __restrict__ WT4,    // [128 k4][1536 j][4 kk] fp32 (this layer)
    const float* __restrict__ bh_l,   // [1536]
    u16* __restrict__ seq_out,        // [512*64][512] bf16 (this layer)
    u64* __restrict__ hx,             // [2 parity][32 pair][512 unit][2 batch]
    int s0, int layer)
{
    __shared__ float hl[2][512];              // [batch-local][unit] fp32
    __shared__ float psum[4][3][2][64];       // [q][gate][batch][unit]

    int blk = blockIdx.x;
    int p   = blk >> 3;           // batch pair 0..31
    int sli = blk & 7;            // unit slice 0..7
    int ub  = sli * 64;
    int tid = threadIdx.x;
    int tu  = tid & 63;           // unit within slice
    int q   = tid >> 6;           // k-quarter 0..3
    int b0  = p * 2;

    int fu = tid & 63, fb = (tid >> 6) & 1;   // finalize mapping (tid<128)
    float bhv0 = 0.f, bhv1 = 0.f, bhv2 = 0.f;
    if (tid < 128) {
        bhv0 = bh_l[ub + fu];
        bhv1 = bh_l[512 + ub + fu];
        bhv2 = bh_l[1024 + ub + fu];
    }

    // ---- hoisted loop-invariant weight loads (R8's exact addresses) ----
    const float4* wbase = (const float4*)WT4;
    const float4* w0 = wbase + (long)(q * 32) * 1536 + (ub + tu);
    const float4* w1 = w0 + 512;
    const float4* w2 = w0 + 1024;
    float4 wr0[32], wr1[32], wr2[32];
#pragma unroll
    for (int k = 0; k < 32; k++) {
        wr0[k] = w0[(long)k * 1536];
        wr1[k] = w1[(long)k * 1536];
        wr2[k] = w2[(long)k * 1536];
    }

    for (int sl = 0; sl < 128; sl++) {
        int s = s0 + sl;

        // ---- gather h (or zero-init at layer start) ----
        if (s == 0) {
            for (int i = tid; i < 1024; i += 256) ((float*)hl)[i] = 0.f;
        } else {
            u32 exp_tag = (u32)(layer * 512 + s);
            u64* slot = hx + (u64)(exp_tag & 1) * 32768;
            int i0 = tid, i1 = tid + 256, i2 = tid + 512, i3 = tid + 768;
            u64* p0 = slot + ((long)p * 512 + (i0 >> 1)) * 2 + (i0 & 1);
            u64* p1 = slot + ((long)p * 512 + (i1 >> 1)) * 2 + (i1 & 1);
            u64* p2 = slot + ((long)p * 512 + (i2 >> 1)) * 2 + (i2 & 1);
            u64* p3 = slot + ((long)p * 512 + (i3 >> 1)) * 2 + (i3 & 1);
            int need = 0xF;
            while (need) {
                if (need & 1) {
                    u64 v = __hip_atomic_fetch_add(p0, 0ull, __ATOMIC_RELAXED, __HIP_MEMORY_SCOPE_AGENT);
                    if ((u32)(v >> 32) == exp_tag) { hl[i0 & 1][i0 >> 1] = __uint_as_float((u32)v); need &= ~1; }
                }
                if (need & 2) {
                    u64 v = __hip_atomic_fetch_add(p1, 0ull, __ATOMIC_RELAXED, __HIP_MEMORY_SCOPE_AGENT);
                    if ((u32)(v >> 32) == exp_tag) { hl[i1 & 1][i1 >> 1] = __uint_as_float((u32)v); need &= ~2; }
                }
                if (need & 4) {
                    u64 v = __hip_atomic_fetch_add(p2, 0ull, __ATOMIC_RELAXED, __HIP_MEMORY_SCOPE_AGENT);
                    if ((u32)(v >> 32) == exp_tag) { hl[i2 & 1][i2 >> 1] = __uint_as_float((u32)v); need &= ~4; }
                }
                if (need & 8) {
                    u64 v = __hip_atomic_fetch_add(p3, 0ull, __ATOMIC_RELAXED, __HIP_MEMORY_SCOPE_AGENT);
                    if ((u32)(v >> 32) == exp_tag) { hl[i3 & 1][i3 >> 1] = __uint_as_float((u32)v); need &= ~8; }
                }
                if (need) __builtin_amdgcn_s_sleep(1);
            }
        }
        __syncthreads();

        // ---- matvec partials: this thread = (unit tu, k-quarter q) ----
        float a00 = 0.f, a01 = 0.f, a10 = 0.f, a11 = 0.f, a20 = 0.f, a21 = 0.f;
        const float4* h0v = (const float4*)hl[0] + q * 32;
        const float4* h1v = (const float4*)hl[1] + q * 32;
#pragma unroll 8
        for (int k = 0; k < 32; k++) {
            float4 wv0 = wr0[k];
            float4 wv1 = wr1[k];
            float4 wv2 = wr2[k];
            float4 hv0 = h0v[k];
            float4 hv1 = h1v[k];
            a00 += wv0.x*hv0.x + wv0.y*hv0.y + wv0.z*hv0.z + wv0.w*hv0.w;
            a01 += wv0.x*hv1.x + wv0.y*hv1.y + wv0.z*hv1.z + wv0.w*hv1.w;
            a10 += wv1.x*hv0.x + wv1.y*hv0.y + wv1.z*hv0.z + wv1.w*hv0.w;
            a11 += wv1.x*hv1.x + wv1.y*hv1.y + wv1.z*hv1.z + wv1.w*hv1.w;
            a20 += wv2.x*hv0.x + wv2.y*hv0.y + wv2.z*hv0.z + wv2.w*hv0.w;
            a21 += wv2.x*hv1.x + wv2.y*hv1.y + wv2.z*hv1.z + wv2.w*hv1.w;
        }
        psum[q][0][0][tu] = a00;  psum[q][0][1][tu] = a01;
        psum[q][1][0][tu] = a10;  psum[q][1][1][tu] = a11;
        psum[q][2][0][tu] = a20;  psum[q][2][1][tu] = a21;
        __syncthreads();

        // ---- finalize on 128 threads ----
        if (tid < 128) {
            float sr = psum[0][0][fb][fu] + psum[1][0][fb][fu] + psum[2][0][fb][fu] + psum[3][0][fb][fu];
            float sz = psum[0][1][fb][fu] + psum[1][1][fb][fu] + psum[2][1][fb][fu] + psum[3][1][fb][fu];
            float sn = psum[0][2][fb][fu] + psum[1][2][fb][fu] + psum[2][2][fb][fu] + psum[3][2][fb][fu];
            const float* g = gi + ((long)sl * 64 + b0 + fb) * 1536;
            float ir = g[ub + fu], iz = g[512 + ub + fu], inn = g[1024 + ub + fu];
            float r  = 1.f / (1.f + expf(-(ir + sr + bhv0)));
            float zg = 1.f / (1.f + expf(-(iz + sz + bhv1)));
            float n  = tanhf(inn + r * (sn + bhv2));
            float hp = hl[fb][ub + fu];
            float hn = (1.f - zg) * n + zg * hp;
            u32 wt = (u32)(layer * 512 + s + 1);
            u64 pv = ((u64)wt << 32) | (u64)__float_as_uint(hn);
            u64* dst = hx + (u64)(wt & 1) * 32768 + ((long)p * 512 + ub + fu) * 2 + fb;
            __hip_atomic_exchange(dst, pv, __ATOMIC_RELAXED, __HIP_MEMORY_SCOPE_AGENT);
            seq_out[((long)s * 64 + b0 + fb) * 512 + ub + fu] = f2b(hn);
        }
        __syncthreads();
    }
}

// ---------------------------------------------------------------------------
__global__ __launch_bounds__(256) void final_kernel(
    const u16* __restrict__ h2, const float* __restrict__ Wf,
    const float* __restrict__ bfin, float* __restrict__ out)
{
    int w = blockIdx.x * 4 + (threadIdx.x >> 6);
    int lane = threadIdx.x & 63;
    const u16* row = h2 + (long)w * 512;
    uint4 hv = *(const uint4*)(row + lane * 8);
    float4 w0 = *(const float4*)(Wf + lane * 8);
    float4 w1 = *(const float4*)(Wf + lane * 8 + 4);
    float sum = b2f(hv.x & 0xffffu) * w0.x + b2fh(hv.x) * w0.y
              + b2f(hv.y & 0xffffu) * w0.z + b2fh(hv.y) * w0.w
              + b2f(hv.z & 0xffffu) * w1.x + b2fh(hv.z) * w1.y
              + b2f(hv.w & 0xffffu) * w1.z + b2fh(hv.w) * w1.w;
#pragma unroll
    for (int off = 32; off > 0; off >>= 1) sum += __shfl_down(sum, off, 64);
    if (lane == 0) {
        int s = w >> 6, b = w & 63;
        out[(long)b * 512 + s] = 1.f / (1.f + expf(-(sum + bfin[0])));
    }
}

// ---------------------------------------------------------------------------
// Launcher — workspace ~172.6 MB
// ---------------------------------------------------------------------------
extern "C" void kernel_launch(void* const* d_in, const int* in_sizes, int n_in,
                              void* d_out, int out_size, void* d_ws, size_t ws_size,
                              hipStream_t stream) {
    const int*   cate  = (const int*)  d_in[0];
    const float* cont  = (const float*)d_in[1];
    const float* emb   = (const float*)d_in[4];
    const float* Wc    = (const float*)d_in[5];
    const float* bc    = (const float*)d_in[6];
    const float* Wcomb = (const float*)d_in[7];
    const float* bcomb = (const float*)d_in[8];
    const float* Wq    = (const float*)d_in[9];
    const float* Wk    = (const float*)d_in[10];
    const float* Wv    = (const float*)d_in[11];
    const float* Wi    = (const float*)d_in[12];
    const float* Wh    = (const float*)d_in[13];
    const float* bi    = (const float*)d_in[14];
    const float* bh    = (const float*)d_in[15];
    const float* Wf    = (const float*)d_in[16];
    const float* bfin  = (const float*)d_in[17];
    float* out = (float*)d_out;
    char* ws = (char*)d_ws;

    u16*   zp    = (u16*)(ws + 0);
    u16*   h2bf  = (u16*)(ws + 0);
    u16*   h1bf  = (u16*)(ws + 33554432);
    float* gi    = (float*)(ws + 67108864);   // 50.3 MB, aliases xbf
    u16*   xbf   = (u16*)(ws + 67108864);
    u16*   QKV   = (u16*)(ws + 117440512);    // [4096][1536] bf16 = 12.58 MB
    u16*   Vt    = (u16*)(ws + 130023424);
    float* Sg    = (float*)(ws + 134217728);  // phase-2 only
    u64*   hx    = (u64*)  (ws + 134217728);  // 512 KB, aliases dead Sg (phase 3)
    u16*   Pg    = (u16*)(ws + 142606336);
    u16*   zT    = (u16*)(ws + 146800640);
    u16*   xc    = (u16*)(ws + 150994944);
    u16*   WcombT= (u16*)(ws + 159383552);
    u16*   WqT   = (u16*)(ws + 160432128);    // contiguous: WqT|WkT|WvT = [1536][512]
    u16*   WkT   = (u16*)(ws + 160956416);
    u16*   WvT   = (u16*)(ws + 161480704);
    u16*   WiB   = (u16*)(ws + 162004992);
    float* pe    = (float*)(ws + 165150720);
    float* WT4   = (float*)(ws + 166199296);  // [2][128][1536][4] fp32, 6.3 MB

    transp_w<<<dim3(16, 8), 256, 0, stream>>>(Wcomb, WcombT, 1024, 512);
    transp_w<<<dim3(8, 8),  256, 0, stream>>>(Wq, WqT, 512, 512);
    transp_w<<<dim3(8, 8),  256, 0, stream>>>(Wk, WkT, 512, 512);
    transp_w<<<dim3(8, 8),  256, 0, stream>>>(Wv, WvT, 512, 512);
    cvt_bf16<<<6144, 256, 0, stream>>>(Wi, WiB, 2L * 1536 * 512);
    wh_transp<<<6144, 256, 0, stream>>>(Wh, WT4);
    pe_kernel<<<512, 256, 0, stream>>>(pe);

    // phase 1
    for (int g = 0; g < 8; g++) {
        embed_kernel<<<4096, 256, 0, stream>>>(cate, cont, emb, Wc, bc, xc, g * 4096);
        gemm_nt<<<dim3(4, 32, 1), 256, 0, stream>>>(
            xc, WcombT, xbf + (long)g * 4096 * 512, 1024, 1024, 1024, 512,
            0, 0, 0, bcomb, pe, 1.f, 1);
    }

    // phase 2 (QKV fused: one N=1536 GEMM per group)
    for (int g = 0; g < 8; g++) {
        const u16* xg = xbf + (long)g * 8 * 512 * 512;
        gemm_nt<<<dim3(12, 32, 1), 256, 0, stream>>>(xg, WqT, QKV, 512,
                                                     512, 512, 1536,
                                                     0, 0, 0, nullptr, nullptr, 1.f, 1);
        // Vt[b][d][s] from V (QKV cols 1024..1535, ld 1536)
        transp_b<<<dim3(8, 8, 8), 256, 0, stream>>>(QKV + 1024, Vt, 512, 512, 1536,
                                                    (long)512 * 1536, 262144, 512);
        // S[b] = Q[b] @ K[b]^T / sqrt(A)
        gemm_nt<<<dim3(4, 4, 8), 256, 0, stream>>>(QKV, QKV + 512, Sg, 512,
                                                   1536, 1536, 512,
                                                   (long)512 * 1536, (long)512 * 1536, 262144,
                                                   nullptr, nullptr,
                                                   0.04419417382415922f, 0);
        softmax_q<<<dim3(8, 8), 64, 0, stream>>>(Sg, Pg);
        // zT[b] = Vt[b] @ P[b]^T
        gemm_nt<<<dim3(4, 4, 8), 256, 0, stream>>>(Vt, Pg, zT, 512, 512, 512, 512,
                                                   262144, 262144, 262144, nullptr, nullptr,
                                                   1.f, 1);
        transp_b<<<dim3(8, 8, 8), 256, 0, stream>>>(zT, zp + (long)g * 8 * 512,
                                                    512, 512, 512, 262144, 512, 32768);
    }

    // phase 3: GRU — unit-split cooperative, hoisted register weights
    zero_kernel<<<1024, 256, 0, stream>>>((float*)hx, 262144);
    for (int l = 0; l < 2; l++) {
        const u16* Aseq = (l == 0) ? zp : h1bf;
        u16* seqOut = (l == 0) ? h1bf : h2bf;
        const u16* WiL = WiB + (long)l * 1536 * 512;
        const float* WT4L = WT4 + (long)l * 786432;
        const float* biL = bi + (long)l * 1536;
        const float* bhL = bh + (long)l * 1536;
        for (int seg = 0; seg < 4; seg++) {
            gemm_nt<<<dim3(12, 64, 1), 256, 0, stream>>>(
                Aseq + (long)seg * 128 * 64 * 512, WiL, gi, 512, 512, 512, 1536,
                0, 0, 0, biL, nullptr, 1.f, 0);
            const float* giP = gi;
            u16* soP = seqOut;
            int s0v = seg * 128;
            int lv = l;
            void* args[] = { (void*)&giP, (void*)&WT4L, (void*)&bhL, (void*)&soP,
                             (void*)&hx, (void*)&s0v, (void*)&lv };
            hipLaunchCooperativeKernel((void*)gru_ex, dim3(256), dim3(256),
                                       args, 0, stream);
        }
    }

    final_kernel<<<8192, 256, 0, stream>>>(h2bf, Wf, bfin, out);
}

// Round 13
// 10231.981 us; speedup vs baseline: 1.8057x; 1.8057x over previous
//
#include <hip/hip_runtime.h>
#include <hip/hip_bf16.h>
#include <math.h>

typedef unsigned short u16;
typedef unsigned int   u32;
typedef unsigned long long u64;
typedef __attribute__((ext_vector_type(8))) short short8;
typedef __attribute__((ext_vector_type(4))) float float4v;

#define BB 64
#define SS 512

// bf16 helpers (RNE)
__device__ __forceinline__ u16 f2b(float f) {
    u32 x = __float_as_uint(f);
    u32 r = (x + 0x7fffu + ((x >> 16) & 1u)) >> 16;
    return (u16)r;
}
__device__ __forceinline__ float b2f(u32 lo16) { return __uint_as_float(lo16 << 16); }
__device__ __forceinline__ float b2fh(u32 v)   { return __uint_as_float(v & 0xffff0000u); }

// ---------------------------------------------------------------------------
__global__ __launch_bounds__(256) void zero_kernel(float* __restrict__ p, int n) {
    int i = blockIdx.x * 256 + threadIdx.x;
    if (i < n) p[i] = 0.f;
}

// ---------------------------------------------------------------------------
__global__ __launch_bounds__(256) void pe_kernel(float* __restrict__ pe) {
    int s = blockIdx.x, j = threadIdx.x;
    float ang = (float)s * powf(10000.0f, -(2.0f * (float)j) / 512.0f);
    pe[s * 512 + 2 * j]     = sinf(ang);
    pe[s * 512 + 2 * j + 1] = cosf(ang);
}

// ---------------------------------------------------------------------------
// fp32 [R][C] -> bf16 [C][R]
// ---------------------------------------------------------------------------
__global__ __launch_bounds__(256) void transp_w(const float* __restrict__ in,
                                                u16* __restrict__ out, int R, int C) {
    __shared__ float t[64][65];
    int r0 = blockIdx.x * 64, c0 = blockIdx.y * 64;
    int tid = threadIdx.x;
    int lr = tid >> 4, lc4 = (tid & 15) * 4;
#pragma unroll
    for (int i = 0; i < 4; i++) {
        int r = lr + i * 16;
        float4 v = *(const float4*)(in + (long)(r0 + r) * C + c0 + lc4);
        t[r][lc4] = v.x; t[r][lc4 + 1] = v.y; t[r][lc4 + 2] = v.z; t[r][lc4 + 3] = v.w;
    }
    __syncthreads();
#pragma unroll
    for (int i = 0; i < 4; i++) {
        int c = lr + i * 16;
        u32 lo = (u32)f2b(t[lc4][c])     | ((u32)f2b(t[lc4 + 1][c]) << 16);
        u32 hi = (u32)f2b(t[lc4 + 2][c]) | ((u32)f2b(t[lc4 + 3][c]) << 16);
        uint2 pk; pk.x = lo; pk.y = hi;
        *(uint2*)(out + (long)(c0 + c) * R + r0 + lc4) = pk;
    }
}

// ---------------------------------------------------------------------------
__global__ __launch_bounds__(256) void cvt_bf16(const float* __restrict__ in,
                                                u16* __restrict__ out, long n) {
    long i = (long)blockIdx.x * 256 + threadIdx.x;
    if (i < n) out[i] = f2b(in[i]);
}

// ---------------------------------------------------------------------------
// Wh [2][1536][512] fp32 -> WT4 [2][128][1536][4] fp32  (k-blocked transpose)
// ---------------------------------------------------------------------------
__global__ __launch_bounds__(256) void wh_transp(const float* __restrict__ Wh,
                                                 float* __restrict__ WT4) {
    long i = (long)blockIdx.x * 256 + threadIdx.x;    // < 2*786432
    if (i >= 2L * 786432) return;
    long l = i / 786432;
    long r = i % 786432;
    int k4 = (int)(r / 6144);
    int rem = (int)(r % 6144);
    int j = rem >> 2, kk = rem & 3;
    WT4[i] = Wh[l * 786432 + (long)j * 512 + k4 * 4 + kk];
}

// ---------------------------------------------------------------------------
// bf16 [nb][R][C(ldin)] -> out[b][c][r] with element strides
// ---------------------------------------------------------------------------
__global__ __launch_bounds__(256) void transp_b(const u16* __restrict__ in,
                                                u16* __restrict__ out,
                                                int R, int C, int ldin,
                                                long sbin, long sb, long sc) {
    __shared__ u32 t[64][65];
    int bz = blockIdx.z;
    in += (long)bz * sbin;
    int r0 = blockIdx.x * 64, c0 = blockIdx.y * 64;
    int tid = threadIdx.x;
    int lr = tid >> 4, lc4 = (tid & 15) * 4;
#pragma unroll
    for (int i = 0; i < 4; i++) {
        int r = lr + i * 16;
        uint2 v = *(const uint2*)(in + (long)(r0 + r) * ldin + c0 + lc4);
        t[r][lc4] = v.x & 0xffffu; t[r][lc4 + 1] = v.x >> 16;
        t[r][lc4 + 2] = v.y & 0xffffu; t[r][lc4 + 3] = v.y >> 16;
    }
    __syncthreads();
#pragma unroll
    for (int i = 0; i < 4; i++) {
        int c = lr + i * 16;
        uint2 pk;
        pk.x = t[lc4][c] | (t[lc4 + 1][c] << 16);
        pk.y = t[lc4 + 2][c] | (t[lc4 + 3][c] << 16);
        *(uint2*)(out + (long)bz * sb + (long)(c0 + c) * sc + r0 + lc4) = pk;
    }
}

// ---------------------------------------------------------------------------
__global__ __launch_bounds__(256) void embed_kernel(
    const int* __restrict__ cate, const float* __restrict__ cont,
    const float* __restrict__ emb, const float* __restrict__ Wc,
    const float* __restrict__ bc, u16* __restrict__ xc, int gbase)
{
    long bs = (long)gbase + blockIdx.x;
    long r  = blockIdx.x;
    __shared__ float cf[6];
    if (threadIdx.x < 6) cf[threadIdx.x] = cont[bs * 6 + threadIdx.x];
    __syncthreads();
    for (int h = threadIdx.x; h < 1024; h += 256) {
        float v;
        if (h < 512) {
            int c = h >> 7, e = h & 127;
            int idx = cate[bs * 4 + c];
            v = emb[((long)c * 1000 + idx) * 128 + e];
        } else {
            int hh = h - 512;
            v = bc[hh];
#pragma unroll
            for (int f = 0; f < 6; f++) v += cf[f] * Wc[f * 512 + hh];
        }
        xc[r * 1024 + h] = f2b(v);
    }
}

// ---------------------------------------------------------------------------
// bf16 MFMA NT GEMM (validated: absmax 0.0)
// ---------------------------------------------------------------------------
__global__ __launch_bounds__(256) void gemm_nt(
    const u16* __restrict__ A, const u16* __restrict__ B, void* __restrict__ Cv,
    int K, int lda, int ldb, int ldc,
    long sA, long sB, long sC,
    const float* __restrict__ bias, const float* __restrict__ pe,
    float alpha, int outBf16)
{
    __shared__ u16 As[128][40];
    __shared__ u16 Bs[128][40];

    A += (long)blockIdx.z * sA;
    B += (long)blockIdx.z * sB;
    int m0 = blockIdx.y * 128, n0 = blockIdx.x * 128;
    int tid = threadIdx.x;
    int lane = tid & 63, wid = tid >> 6;
    int wm = (wid >> 1) * 64, wn = (wid & 1) * 64;
    int mrow = lane & 15, q8 = (lane >> 4) * 8;

    float4v acc[4][4];
#pragma unroll
    for (int i = 0; i < 4; i++)
#pragma unroll
        for (int j = 0; j < 4; j++) { float4v z = {0.f, 0.f, 0.f, 0.f}; acc[i][j] = z; }

    for (int k0 = 0; k0 < K; k0 += 32) {
        {
            int r = tid >> 2, sg = tid & 3;
            *(short8*)&As[r][sg * 8] = *(const short8*)(A + (long)(m0 + r) * lda + k0 + sg * 8);
            *(short8*)&Bs[r][sg * 8] = *(const short8*)(B + (long)(n0 + r) * ldb + k0 + sg * 8);
            r = (tid + 256) >> 2;
            *(short8*)&As[r][sg * 8] = *(const short8*)(A + (long)(m0 + r) * lda + k0 + sg * 8);
            *(short8*)&Bs[r][sg * 8] = *(const short8*)(B + (long)(n0 + r) * ldb + k0 + sg * 8);
        }
        __syncthreads();
        short8 af[4], bfr[4];
#pragma unroll
        for (int t = 0; t < 4; t++) {
            af[t]  = *(const short8*)&As[wm + t * 16 + mrow][q8];
            bfr[t] = *(const short8*)&Bs[wn + t * 16 + mrow][q8];
        }
#pragma unroll
        for (int i = 0; i < 4; i++)
#pragma unroll
            for (int j = 0; j < 4; j++)
                acc[i][j] = __builtin_amdgcn_mfma_f32_16x16x32_bf16(af[i], bfr[j], acc[i][j], 0, 0, 0);
        __syncthreads();
    }

    int col = lane & 15, quad = lane >> 4;
    u16*  Cb = (u16*)Cv  + (outBf16 ? (long)blockIdx.z * sC : 0);
    float* Cf = (float*)Cv + (outBf16 ? 0 : (long)blockIdx.z * sC);
#pragma unroll
    for (int i = 0; i < 4; i++)
#pragma unroll
        for (int j = 0; j < 4; j++) {
#pragma unroll
            for (int rr = 0; rr < 4; rr++) {
                int gm = m0 + wm + i * 16 + quad * 4 + rr;
                int gn = n0 + wn + j * 16 + col;
                float v = acc[i][j][rr] * alpha;
                if (bias) v += bias[gn];
                if (pe)   v += pe[(long)(gm & 511) * 512 + gn];
                if (outBf16) Cb[(long)gm * ldc + gn] = f2b(v);
                else         Cf[(long)gm * ldc + gn] = v;
            }
        }
}

// ---------------------------------------------------------------------------
// Softmax over QUERY axis fp32 -> bf16
// ---------------------------------------------------------------------------
__global__ __launch_bounds__(64) void softmax_q(const float* __restrict__ S,
                                                u16* __restrict__ P) {
    int b = blockIdx.x;
    int k = blockIdx.y * 64 + threadIdx.x;
    const float* p = S + (long)b * 262144 + k;
    u16* o = P + (long)b * 262144 + k;
    float m = -1e30f;
    for (int q = 0; q < 512; q++) m = fmaxf(m, p[(long)q * 512]);
    float sum = 0.f;
    for (int q = 0; q < 512; q++) sum += expf(p[(long)q * 512] - m);
    float inv = 1.f / sum;
    for (int q = 0; q < 512; q++) o[(long)q * 512] = f2b(expf(p[(long)q * 512] - m) * inv);
}

// ---------------------------------------------------------------------------
// Unit-split cooperative GRU — VERBATIM R8 (validated absmax 0.0, 1.0ms/seg):
// per-step global weight loads (unroll 8), fetch_add tagged gather, atomic
// exchange writes. ONE change: block-index remap p=blk&31, sli=blk>>5 —
// a pure bijection (cooperative blocks are symmetric), chosen so the 8
// exchange-partner blocks of pair p are {p, p+32, ...} ≡ p (mod 8): if
// dispatch is round-robin across the 8 XCDs, pair-mates share an XCD and
// the per-step hx RMWs become XCD-local (perf heuristic only; correctness
// does not depend on placement).
// NOTE: do NOT register-hoist the weight loads — R9/R10/R12 all failed
// numerically whenever the weight arrays were truly register-promoted.
// ---------------------------------------------------------------------------
__global__ __launch_bounds__(256, 1) void gru_ex(
    const float* __restrict__ gi,     // [128][64][1536] fp32 (includes bi)
    const float* __restrict__ WT4,    // [128 k4][1536 j][4 kk] fp32 (this layer)
    const float* __restrict__ bh_l,   // [1536]
    u16* __restrict__ seq_out,        // [512*64][512] bf16 (this layer)
    u64* __restrict__ hx,             // [2 parity][32 pair][512 unit][2 batch]
    int s0, int layer)
{
    __shared__ float hl[2][512];              // [batch-local][unit] fp32
    __shared__ float psum[4][3][2][64];       // [q][gate][batch][unit]

    int blk = blockIdx.x;
    int p   = blk & 31;           // batch pair 0..31 (XCD-local remap)
    int sli = blk >> 5;           // unit slice 0..7
    int ub  = sli * 64;
    int tid = threadIdx.x;
    int tu  = tid & 63;           // unit within slice
    int q   = tid >> 6;           // k-quarter 0..3
    int b0  = p * 2;

    int fu = tid & 63, fb = (tid >> 6) & 1;   // finalize mapping (tid<128)
    float bhv0 = 0.f, bhv1 = 0.f, bhv2 = 0.f;
    if (tid < 128) {
        bhv0 = bh_l[ub + fu];
        bhv1 = bh_l[512 + ub + fu];
        bhv2 = bh_l[1024 + ub + fu];
    }

    const float4* wbase = (const float4*)WT4;

    for (int sl = 0; sl < 128; sl++) {
        int s = s0 + sl;

        // ---- gather h (or zero-init at layer start) ----
        if (s == 0) {
            for (int i = tid; i < 1024; i += 256) ((float*)hl)[i] = 0.f;
        } else {
            u32 exp_tag = (u32)(layer * 512 + s);
            u64* slot = hx + (u64)(exp_tag & 1) * 32768;
            int i0 = tid, i1 = tid + 256, i2 = tid + 512, i3 = tid + 768;
            u64* p0 = slot + ((long)p * 512 + (i0 >> 1)) * 2 + (i0 & 1);
            u64* p1 = slot + ((long)p * 512 + (i1 >> 1)) * 2 + (i1 & 1);
            u64* p2 = slot + ((long)p * 512 + (i2 >> 1)) * 2 + (i2 & 1);
            u64* p3 = slot + ((long)p * 512 + (i3 >> 1)) * 2 + (i3 & 1);
            int need = 0xF;
            while (need) {
                if (need & 1) {
                    u64 v = __hip_atomic_fetch_add(p0, 0ull, __ATOMIC_RELAXED, __HIP_MEMORY_SCOPE_AGENT);
                    if ((u32)(v >> 32) == exp_tag) { hl[i0 & 1][i0 >> 1] = __uint_as_float((u32)v); need &= ~1; }
                }
                if (need & 2) {
                    u64 v = __hip_atomic_fetch_add(p1, 0ull, __ATOMIC_RELAXED, __HIP_MEMORY_SCOPE_AGENT);
                    if ((u32)(v >> 32) == exp_tag) { hl[i1 & 1][i1 >> 1] = __uint_as_float((u32)v); need &= ~2; }
                }
                if (need & 4) {
                    u64 v = __hip_atomic_fetch_add(p2, 0ull, __ATOMIC_RELAXED, __HIP_MEMORY_SCOPE_AGENT);
                    if ((u32)(v >> 32) == exp_tag) { hl[i2 & 1][i2 >> 1] = __uint_as_float((u32)v); need &= ~4; }
                }
                if (need & 8) {
                    u64 v = __hip_atomic_fetch_add(p3, 0ull, __ATOMIC_RELAXED, __HIP_MEMORY_SCOPE_AGENT);
                    if ((u32)(v >> 32) == exp_tag) { hl[i3 & 1][i3 >> 1] = __uint_as_float((u32)v); need &= ~8; }
                }
                if (need) __builtin_amdgcn_s_sleep(1);
            }
        }
        __syncthreads();

        // ---- matvec partials: this thread = (unit tu, k-quarter q) ----
        float a00 = 0.f, a01 = 0.f, a10 = 0.f, a11 = 0.f, a20 = 0.f, a21 = 0.f;
        const float4* h0v = (const float4*)hl[0] + q * 32;
        const float4* h1v = (const float4*)hl[1] + q * 32;
        const float4* w0 = wbase + (long)(q * 32) * 1536 + (ub + tu);
        const float4* w1 = w0 + 512;
        const float4* w2 = w0 + 1024;
#pragma unroll 8
        for (int k = 0; k < 32; k++) {
            float4 wv0 = w0[(long)k * 1536];
            float4 wv1 = w1[(long)k * 1536];
            float4 wv2 = w2[(long)k * 1536];
            float4 hv0 = h0v[k];
            float4 hv1 = h1v[k];
            a00 += wv0.x*hv0.x + wv0.y*hv0.y + wv0.z*hv0.z + wv0.w*hv0.w;
            a01 += wv0.x*hv1.x + wv0.y*hv1.y + wv0.z*hv1.z + wv0.w*hv1.w;
            a10 += wv1.x*hv0.x + wv1.y*hv0.y + wv1.z*hv0.z + wv1.w*hv0.w;
            a11 += wv1.x*hv1.x + wv1.y*hv1.y + wv1.z*hv1.z + wv1.w*hv1.w;
            a20 += wv2.x*hv0.x + wv2.y*hv0.y + wv2.z*hv0.z + wv2.w*hv0.w;
            a21 += wv2.x*hv1.x + wv2.y*hv1.y + wv2.z*hv1.z + wv2.w*hv1.w;
        }
        psum[q][0][0][tu] = a00;  psum[q][0][1][tu] = a01;
        psum[q][1][0][tu] = a10;  psum[q][1][1][tu] = a11;
        psum[q][2][0][tu] = a20;  psum[q][2][1][tu] = a21;
        __syncthreads();

        // ---- finalize on 128 threads ----
        if (tid < 128) {
            float sr = psum[0][0][fb][fu] + psum[1][0][fb][fu] + psum[2][0][fb][fu] + psum[3][0][fb][fu];
            float sz = psum[0][1][fb][fu] + psum[1][1][fb][fu] + psum[2][1][fb][fu] + psum[3][1][fb][fu];
            float sn = psum[0][2][fb][fu] + psum[1][2][fb][fu] + psum[2][2][fb][fu] + psum[3][2][fb][fu];
            const float* g = gi + ((long)sl * 64 + b0 + fb) * 1536;
            float ir = g[ub + fu], iz = g[512 + ub + fu], inn = g[1024 + ub + fu];
            float r  = 1.f / (1.f + expf(-(ir + sr + bhv0)));
            float zg = 1.f / (1.f + expf(-(iz + sz + bhv1)));
            float n  = tanhf(inn + r * (sn + bhv2));
            float hp = hl[fb][ub + fu];
            float hn = (1.f - zg) * n + zg * hp;
            u32 wt = (u32)(layer * 512 + s + 1);
            u64 pv = ((u64)wt << 32) | (u64)__float_as_uint(hn);
            u64* dst = hx + (u64)(wt & 1) * 32768 + ((long)p * 512 + ub + fu) * 2 + fb;
            __hip_atomic_exchange(dst, pv, __ATOMIC_RELAXED, __HIP_MEMORY_SCOPE_AGENT);
            seq_out[((long)s * 64 + b0 + fb) * 512 + ub + fu] = f2b(hn);
        }
        __syncthreads();
    }
}

// ---------------------------------------------------------------------------
__global__ __launch_bounds__(256) void final_kernel(
    const u16* __restrict__ h2, const float* __restrict__ Wf,
    const float* __restrict__ bfin, float* __restrict__ out)
{
    int w = blockIdx.x * 4 + (threadIdx.x >> 6);
    int lane = threadIdx.x & 63;
    const u16* row = h2 + (long)w * 512;
    uint4 hv = *(const uint4*)(row + lane * 8);
    float4 w0 = *(const float4*)(Wf + lane * 8);
    float4 w1 = *(const float4*)(Wf + lane * 8 + 4);
    float sum = b2f(hv.x & 0xffffu) * w0.x + b2fh(hv.x) * w0.y
              + b2f(hv.y & 0xffffu) * w0.z + b2fh(hv.y) * w0.w
              + b2f(hv.z & 0xffffu) * w1.x + b2fh(hv.z) * w1.y
              + b2f(hv.w & 0xffffu) * w1.z + b2fh(hv.w) * w1.w;
#pragma unroll
    for (int off = 32; off > 0; off >>= 1) sum += __shfl_down(sum, off, 64);
    if (lane == 0) {
        int s = w >> 6, b = w & 63;
        out[(long)b * 512 + s] = 1.f / (1.f + expf(-(sum + bfin[0])));
    }
}

// ---------------------------------------------------------------------------
// Launcher — workspace ~172.6 MB
// ---------------------------------------------------------------------------
extern "C" void kernel_launch(void* const* d_in, const int* in_sizes, int n_in,
                              void* d_out, int out_size, void* d_ws, size_t ws_size,
                              hipStream_t stream) {
    const int*   cate  = (const int*)  d_in[0];
    const float* cont  = (const float*)d_in[1];
    const float* emb   = (const float*)d_in[4];
    const float* Wc    = (const float*)d_in[5];
    const float* bc    = (const float*)d_in[6];
    const float* Wcomb = (const float*)d_in[7];
    const float* bcomb = (const float*)d_in[8];
    const float* Wq    = (const float*)d_in[9];
    const float* Wk    = (const float*)d_in[10];
    const float* Wv    = (const float*)d_in[11];
    const float* Wi    = (const float*)d_in[12];
    const float* Wh    = (const float*)d_in[13];
    const float* bi    = (const float*)d_in[14];
    const float* bh    = (const float*)d_in[15];
    const float* Wf    = (const float*)d_in[16];
    const float* bfin  = (const float*)d_in[17];
    float* out = (float*)d_out;
    char* ws = (char*)d_ws;

    u16*   zp    = (u16*)(ws + 0);
    u16*   h2bf  = (u16*)(ws + 0);
    u16*   h1bf  = (u16*)(ws + 33554432);
    float* gi    = (float*)(ws + 67108864);   // 50.3 MB, aliases xbf
    u16*   xbf   = (u16*)(ws + 67108864);
    u16*   QKV   = (u16*)(ws + 117440512);    // [4096][1536] bf16 = 12.58 MB
    u16*   Vt    = (u16*)(ws + 130023424);
    float* Sg    = (float*)(ws + 134217728);  // phase-2 only
    u64*   hx    = (u64*)  (ws + 134217728);  // 512 KB, aliases dead Sg (phase 3)
    u16*   Pg    = (u16*)(ws + 142606336);
    u16*   zT    = (u16*)(ws + 146800640);
    u16*   xc    = (u16*)(ws + 150994944);
    u16*   WcombT= (u16*)(ws + 159383552);
    u16*   WqT   = (u16*)(ws + 160432128);    // contiguous: WqT|WkT|WvT = [1536][512]
    u16*   WkT   = (u16*)(ws + 160956416);
    u16*   WvT   = (u16*)(ws + 161480704);
    u16*   WiB   = (u16*)(ws + 162004992);
    float* pe    = (float*)(ws + 165150720);
    float* WT4   = (float*)(ws + 166199296);  // [2][128][1536][4] fp32, 6.3 MB

    transp_w<<<dim3(16, 8), 256, 0, stream>>>(Wcomb, WcombT, 1024, 512);
    transp_w<<<dim3(8, 8),  256, 0, stream>>>(Wq, WqT, 512, 512);
    transp_w<<<dim3(8, 8),  256, 0, stream>>>(Wk, WkT, 512, 512);
    transp_w<<<dim3(8, 8),  256, 0, stream>>>(Wv, WvT, 512, 512);
    cvt_bf16<<<6144, 256, 0, stream>>>(Wi, WiB, 2L * 1536 * 512);
    wh_transp<<<6144, 256, 0, stream>>>(Wh, WT4);
    pe_kernel<<<512, 256, 0, stream>>>(pe);

    // phase 1
    for (int g = 0; g < 8; g++) {
        embed_kernel<<<4096, 256, 0, stream>>>(cate, cont, emb, Wc, bc, xc, g * 4096);
        gemm_nt<<<dim3(4, 32, 1), 256, 0, stream>>>(
            xc, WcombT, xbf + (long)g * 4096 * 512, 1024, 1024, 1024, 512,
            0, 0, 0, bcomb, pe, 1.f, 1);
    }

    // phase 2 (QKV fused: one N=1536 GEMM per group)
    for (int g = 0; g < 8; g++) {
        const u16* xg = xbf + (long)g * 8 * 512 * 512;
        gemm_nt<<<dim3(12, 32, 1), 256, 0, stream>>>(xg, WqT, QKV, 512,
                                                     512, 512, 1536,
                                                     0, 0, 0, nullptr, nullptr, 1.f, 1);
        // Vt[b][d][s] from V (QKV cols 1024..1535, ld 1536)
        transp_b<<<dim3(8, 8, 8), 256, 0, stream>>>(QKV + 1024, Vt, 512, 512, 1536,
                                                    (long)512 * 1536, 262144, 512);
        // S[b] = Q[b] @ K[b]^T / sqrt(A)
        gemm_nt<<<dim3(4, 4, 8), 256, 0, stream>>>(QKV, QKV + 512, Sg, 512,
                                                   1536, 1536, 512,
                                                   (long)512 * 1536, (long)512 * 1536, 262144,
                                                   nullptr, nullptr,
                                                   0.04419417382415922f, 0);
        softmax_q<<<dim3(8, 8), 64, 0, stream>>>(Sg, Pg);
        // zT[b] = Vt[b] @ P[b]^T
        gemm_nt<<<dim3(4, 4, 8), 256, 0, stream>>>(Vt, Pg, zT, 512, 512, 512, 512,
                                                   262144, 262144, 262144, nullptr, nullptr,
                                                   1.f, 1);
        transp_b<<<dim3(8, 8, 8), 256, 0, stream>>>(zT, zp + (long)g * 8 * 512,
                                                    512, 512, 512, 262144, 512, 32768);
    }

    // phase 3: GRU — unit-split cooperative (R8 kernel, XCD-local remap)
    zero_kernel<<<1024, 256, 0, stream>>>((float*)hx, 262144);
    for (int l = 0; l < 2; l++) {
        const u16* Aseq = (l == 0) ? zp : h1bf;
        u16* seqOut = (l == 0) ? h1bf : h2bf;
        const u16* WiL = WiB + (long)l * 1536 * 512;
        const float* WT4L = WT4 + (long)l * 786432;
        const float* biL = bi + (long)l * 1536;
        const float* bhL = bh + (long)l * 1536;
        for (int seg = 0; seg < 4; seg++) {
            gemm_nt<<<dim3(12, 64, 1), 256, 0, stream>>>(
                Aseq + (long)seg * 128 * 64 * 512, WiL, gi, 512, 512, 512, 1536,
                0, 0, 0, biL, nullptr, 1.f, 0);
            const float* giP = gi;
            u16* soP = seqOut;
            int s0v = seg * 128;
            int lv = l;
            void* args[] = { (void*)&giP, (void*)&WT4L, (void*)&bhL, (void*)&soP,
                             (void*)&hx, (void*)&s0v, (void*)&lv };
            hipLaunchCooperativeKernel((void*)gru_ex, dim3(256), dim3(256),
                                       args, 0, stream);
        }
    }

    final_kernel<<<8192, 256, 0, stream>>>(h2bf, Wf, bfin, out);
}

// Round 14
// 8355.562 us; speedup vs baseline: 2.2112x; 1.2246x over previous
//
#include <hip/hip_runtime.h>
#include <hip/hip_bf16.h>
#include <math.h>

typedef unsigned short u16;
typedef unsigned int   u32;
typedef unsigned long long u64;
typedef __attribute__((ext_vector_type(8))) short short8;
typedef __attribute__((ext_vector_type(4))) float float4v;

#define BB 64
#define SS 512

// bf16 helpers (RNE)
__device__ __forceinline__ u16 f2b(float f) {
    u32 x = __float_as_uint(f);
    u32 r = (x + 0x7fffu + ((x >> 16) & 1u)) >> 16;
    return (u16)r;
}
__device__ __forceinline__ float b2f(u32 lo16) { return __uint_as_float(lo16 << 16); }
__device__ __forceinline__ float b2fh(u32 v)   { return __uint_as_float(v & 0xffff0000u); }

// ---------------------------------------------------------------------------
__global__ __launch_bounds__(256) void zero_kernel(float* __restrict__ p, int n) {
    int i = blockIdx.x * 256 + threadIdx.x;
    if (i < n) p[i] = 0.f;
}

// ---------------------------------------------------------------------------
__global__ __launch_bounds__(256) void pe_kernel(float* __restrict__ pe) {
    int s = blockIdx.x, j = threadIdx.x;
    float ang = (float)s * powf(10000.0f, -(2.0f * (float)j) / 512.0f);
    pe[s * 512 + 2 * j]     = sinf(ang);
    pe[s * 512 + 2 * j + 1] = cosf(ang);
}

// ---------------------------------------------------------------------------
// fp32 [R][C] -> bf16 [C][R]
// ---------------------------------------------------------------------------
__global__ __launch_bounds__(256) void transp_w(const float* __restrict__ in,
                                                u16* __restrict__ out, int R, int C) {
    __shared__ float t[64][65];
    int r0 = blockIdx.x * 64, c0 = blockIdx.y * 64;
    int tid = threadIdx.x;
    int lr = tid >> 4, lc4 = (tid & 15) * 4;
#pragma unroll
    for (int i = 0; i < 4; i++) {
        int r = lr + i * 16;
        float4 v = *(const float4*)(in + (long)(r0 + r) * C + c0 + lc4);
        t[r][lc4] = v.x; t[r][lc4 + 1] = v.y; t[r][lc4 + 2] = v.z; t[r][lc4 + 3] = v.w;
    }
    __syncthreads();
#pragma unroll
    for (int i = 0; i < 4; i++) {
        int c = lr + i * 16;
        u32 lo = (u32)f2b(t[lc4][c])     | ((u32)f2b(t[lc4 + 1][c]) << 16);
        u32 hi = (u32)f2b(t[lc4 + 2][c]) | ((u32)f2b(t[lc4 + 3][c]) << 16);
        uint2 pk; pk.x = lo; pk.y = hi;
        *(uint2*)(out + (long)(c0 + c) * R + r0 + lc4) = pk;
    }
}

// ---------------------------------------------------------------------------
__global__ __launch_bounds__(256) void cvt_bf16(const float* __restrict__ in,
                                                u16* __restrict__ out, long n) {
    long i = (long)blockIdx.x * 256 + threadIdx.x;
    if (i < n) out[i] = f2b(in[i]);
}

// ---------------------------------------------------------------------------
// Wh [2][1536][512] fp32 -> WT4 [2][128][1536][4] fp32  (k-blocked transpose)
// ---------------------------------------------------------------------------
__global__ __launch_bounds__(256) void wh_transp(const float* __restrict__ Wh,
                                                 float* __restrict__ WT4) {
    long i = (long)blockIdx.x * 256 + threadIdx.x;    // < 2*786432
    if (i >= 2L * 786432) return;
    long l = i / 786432;
    long r = i % 786432;
    int k4 = (int)(r / 6144);
    int rem = (int)(r % 6144);
    int j = rem >> 2, kk = rem & 3;
    WT4[i] = Wh[l * 786432 + (long)j * 512 + k4 * 4 + kk];
}

// ---------------------------------------------------------------------------
// bf16 [nb][R][C(ldin)] -> out[b][c][r] with element strides
// ---------------------------------------------------------------------------
__global__ __launch_bounds__(256) void transp_b(const u16* __restrict__ in,
                                                u16* __restrict__ out,
                                                int R, int C, int ldin,
                                                long sbin, long sb, long sc) {
    __shared__ u32 t[64][65];
    int bz = blockIdx.z;
    in += (long)bz * sbin;
    int r0 = blockIdx.x * 64, c0 = blockIdx.y * 64;
    int tid = threadIdx.x;
    int lr = tid >> 4, lc4 = (tid & 15) * 4;
#pragma unroll
    for (int i = 0; i < 4; i++) {
        int r = lr + i * 16;
        uint2 v = *(const uint2*)(in + (long)(r0 + r) * ldin + c0 + lc4);
        t[r][lc4] = v.x & 0xffffu; t[r][lc4 + 1] = v.x >> 16;
        t[r][lc4 + 2] = v.y & 0xffffu; t[r][lc4 + 3] = v.y >> 16;
    }
    __syncthreads();
#pragma unroll
    for (int i = 0; i < 4; i++) {
        int c = lr + i * 16;
        uint2 pk;
        pk.x = t[lc4][c] | (t[lc4 + 1][c] << 16);
        pk.y = t[lc4 + 2][c] | (t[lc4 + 3][c] << 16);
        *(uint2*)(out + (long)bz * sb + (long)(c0 + c) * sc + r0 + lc4) = pk;
    }
}

// ---------------------------------------------------------------------------
__global__ __launch_bounds__(256) void embed_kernel(
    const int* __restrict__ cate, const float* __restrict__ cont,
    const float* __restrict__ emb, const float* __restrict__ Wc,
    const float* __restrict__ bc, u16* __restrict__ xc, int gbase)
{
    long bs = (long)gbase + blockIdx.x;
    long r  = blockIdx.x;
    __shared__ float cf[6];
    if (threadIdx.x < 6) cf[threadIdx.x] = cont[bs * 6 + threadIdx.x];
    __syncthreads();
    for (int h = threadIdx.x; h < 1024; h += 256) {
        float v;
        if (h < 512) {
            int c = h >> 7, e = h & 127;
            int idx = cate[bs * 4 + c];
            v = emb[((long)c * 1000 + idx) * 128 + e];
        } else {
            int hh = h - 512;
            v = bc[hh];
#pragma unroll
            for (int f = 0; f < 6; f++) v += cf[f] * Wc[f * 512 + hh];
        }
        xc[r * 1024 + h] = f2b(v);
    }
}

// ---------------------------------------------------------------------------
// bf16 MFMA NT GEMM (validated: absmax 0.0)
// ---------------------------------------------------------------------------
__global__ __launch_bounds__(256) void gemm_nt(
    const u16* __restrict__ A, const u16* __restrict__ B, void* __restrict__ Cv,
    int K, int lda, int ldb, int ldc,
    long sA, long sB, long sC,
    const float* __restrict__ bias, const float* __restrict__ pe,
    float alpha, int outBf16)
{
    __shared__ u16 As[128][40];
    __shared__ u16 Bs[128][40];

    A += (long)blockIdx.z * sA;
    B += (long)blockIdx.z * sB;
    int m0 = blockIdx.y * 128, n0 = blockIdx.x * 128;
    int tid = threadIdx.x;
    int lane = tid & 63, wid = tid >> 6;
    int wm = (wid >> 1) * 64, wn = (wid & 1) * 64;
    int mrow = lane & 15, q8 = (lane >> 4) * 8;

    float4v acc[4][4];
#pragma unroll
    for (int i = 0; i < 4; i++)
#pragma unroll
        for (int j = 0; j < 4; j++) { float4v z = {0.f, 0.f, 0.f, 0.f}; acc[i][j] = z; }

    for (int k0 = 0; k0 < K; k0 += 32) {
        {
            int r = tid >> 2, sg = tid & 3;
            *(short8*)&As[r][sg * 8] = *(const short8*)(A + (long)(m0 + r) * lda + k0 + sg * 8);
            *(short8*)&Bs[r][sg * 8] = *(const short8*)(B + (long)(n0 + r) * ldb + k0 + sg * 8);
            r = (tid + 256) >> 2;
            *(short8*)&As[r][sg * 8] = *(const short8*)(A + (long)(m0 + r) * lda + k0 + sg * 8);
            *(short8*)&Bs[r][sg * 8] = *(const short8*)(B + (long)(n0 + r) * ldb + k0 + sg * 8);
        }
        __syncthreads();
        short8 af[4], bfr[4];
#pragma unroll
        for (int t = 0; t < 4; t++) {
            af[t]  = *(const short8*)&As[wm + t * 16 + mrow][q8];
            bfr[t] = *(const short8*)&Bs[wn + t * 16 + mrow][q8];
        }
#pragma unroll
        for (int i = 0; i < 4; i++)
#pragma unroll
            for (int j = 0; j < 4; j++)
                acc[i][j] = __builtin_amdgcn_mfma_f32_16x16x32_bf16(af[i], bfr[j], acc[i][j], 0, 0, 0);
        __syncthreads();
    }

    int col = lane & 15, quad = lane >> 4;
    u16*  Cb = (u16*)Cv  + (outBf16 ? (long)blockIdx.z * sC : 0);
    float* Cf = (float*)Cv + (outBf16 ? 0 : (long)blockIdx.z * sC);
#pragma unroll
    for (int i = 0; i < 4; i++)
#pragma unroll
        for (int j = 0; j < 4; j++) {
#pragma unroll
            for (int rr = 0; rr < 4; rr++) {
                int gm = m0 + wm + i * 16 + quad * 4 + rr;
                int gn = n0 + wn + j * 16 + col;
                float v = acc[i][j][rr] * alpha;
                if (bias) v += bias[gn];
                if (pe)   v += pe[(long)(gm & 511) * 512 + gn];
                if (outBf16) Cb[(long)gm * ldc + gn] = f2b(v);
                else         Cf[(long)gm * ldc + gn] = v;
            }
        }
}

// ---------------------------------------------------------------------------
// Softmax over QUERY axis fp32 -> bf16
// ---------------------------------------------------------------------------
__global__ __launch_bounds__(64) void softmax_q(const float* __restrict__ S,
                                                u16* __restrict__ P) {
    int b = blockIdx.x;
    int k = blockIdx.y * 64 + threadIdx.x;
    const float* p = S + (long)b * 262144 + k;
    u16* o = P + (long)b * 262144 + k;
    float m = -1e30f;
    for (int q = 0; q < 512; q++) m = fmaxf(m, p[(long)q * 512]);
    float sum = 0.f;
    for (int q = 0; q < 512; q++) sum += expf(p[(long)q * 512] - m);
    float inv = 1.f / sum;
    for (int q = 0; q < 512; q++) o[(long)q * 512] = f2b(expf(p[(long)q * 512] - m) * inv);
}

// ---------------------------------------------------------------------------
// Unit-split cooperative GRU — R13's validated structure (passed, absmax 0.0).
// Two perf-only changes:
//  1. Gate-0 weight slice (128 KB fp32) cached in LDS once per segment
//     (R5 proved >64KB static LDS works: LDS_Block_Size=146944 ran fine).
//     Same fp32 bits, different transport — numerics unchanged.
//  2. Gather polls with relaxed agent atomic LOADS (no line-exclusive RMW
//     serialization across the 8 consumer blocks per line). Single-variable
//     test of the load path (R12 was confounded by register-weights).
// Weight register-hoisting remains BANNED (R9/R10/R12: 3/3 numerical fails).
// Grid 256 = 32 pairs x 8 slices, p=blk&31 XCD-local remap (R13).
// ---------------------------------------------------------------------------
__global__ __launch_bounds__(256, 1) void gru_ex(
    const float* __restrict__ gi,     // [128][64][1536] fp32 (includes bi)
    const float* __restrict__ WT4,    // [128 k4][1536 j][4 kk] fp32 (this layer)
    const float* __restrict__ bh_l,   // [1536]
    u16* __restrict__ seq_out,        // [512*64][512] bf16 (this layer)
    u64* __restrict__ hx,             // [2 parity][32 pair][512 unit][2 batch]
    int s0, int layer)
{
    __shared__ float hl[2][512];              // [batch-local][unit] fp32   4 KB
    __shared__ float psum[4][3][2][64];       // [q][gate][batch][unit]     6 KB
    __shared__ float4 wlds[8192];             // gate-0 slice [128 k4][64 u] 128 KB

    int blk = blockIdx.x;
    int p   = blk & 31;           // batch pair 0..31 (XCD-local remap)
    int sli = blk >> 5;           // unit slice 0..7
    int ub  = sli * 64;
    int tid = threadIdx.x;
    int tu  = tid & 63;           // unit within slice
    int q   = tid >> 6;           // k-quarter 0..3
    int b0  = p * 2;

    int fu = tid & 63, fb = (tid >> 6) & 1;   // finalize mapping (tid<128)
    float bhv0 = 0.f, bhv1 = 0.f, bhv2 = 0.f;
    if (tid < 128) {
        bhv0 = bh_l[ub + fu];
        bhv1 = bh_l[512 + ub + fu];
        bhv2 = bh_l[1024 + ub + fu];
    }

    const float4* wbase = (const float4*)WT4;

    // ---- fill gate-0 LDS cache once per segment (coalesced) ----
    for (int i = tid; i < 8192; i += 256) {
        int k4 = i >> 6, u = i & 63;
        wlds[i] = wbase[(long)k4 * 1536 + ub + u];
    }
    __syncthreads();

    for (int sl = 0; sl < 128; sl++) {
        int s = s0 + sl;

        // ---- gather h (or zero-init at layer start) ----
        if (s == 0) {
            for (int i = tid; i < 1024; i += 256) ((float*)hl)[i] = 0.f;
        } else {
            u32 exp_tag = (u32)(layer * 512 + s);
            u64* slot = hx + (u64)(exp_tag & 1) * 32768;
            int i0 = tid, i1 = tid + 256, i2 = tid + 512, i3 = tid + 768;
            u64* p0 = slot + ((long)p * 512 + (i0 >> 1)) * 2 + (i0 & 1);
            u64* p1 = slot + ((long)p * 512 + (i1 >> 1)) * 2 + (i1 & 1);
            u64* p2 = slot + ((long)p * 512 + (i2 >> 1)) * 2 + (i2 & 1);
            u64* p3 = slot + ((long)p * 512 + (i3 >> 1)) * 2 + (i3 & 1);
            int need = 0xF;
            while (need) {
                if (need & 1) {
                    u64 v = __hip_atomic_load(p0, __ATOMIC_RELAXED, __HIP_MEMORY_SCOPE_AGENT);
                    if ((u32)(v >> 32) == exp_tag) { hl[i0 & 1][i0 >> 1] = __uint_as_float((u32)v); need &= ~1; }
                }
                if (need & 2) {
                    u64 v = __hip_atomic_load(p1, __ATOMIC_RELAXED, __HIP_MEMORY_SCOPE_AGENT);
                    if ((u32)(v >> 32) == exp_tag) { hl[i1 & 1][i1 >> 1] = __uint_as_float((u32)v); need &= ~2; }
                }
                if (need & 4) {
                    u64 v = __hip_atomic_load(p2, __ATOMIC_RELAXED, __HIP_MEMORY_SCOPE_AGENT);
                    if ((u32)(v >> 32) == exp_tag) { hl[i2 & 1][i2 >> 1] = __uint_as_float((u32)v); need &= ~4; }
                }
                if (need & 8) {
                    u64 v = __hip_atomic_load(p3, __ATOMIC_RELAXED, __HIP_MEMORY_SCOPE_AGENT);
                    if ((u32)(v >> 32) == exp_tag) { hl[i3 & 1][i3 >> 1] = __uint_as_float((u32)v); need &= ~8; }
                }
                if (need) __builtin_amdgcn_s_sleep(1);
            }
        }
        __syncthreads();

        // ---- matvec partials: this thread = (unit tu, k-quarter q) ----
        float a00 = 0.f, a01 = 0.f, a10 = 0.f, a11 = 0.f, a20 = 0.f, a21 = 0.f;
        const float4* h0v = (const float4*)hl[0] + q * 32;
        const float4* h1v = (const float4*)hl[1] + q * 32;
        const float4* wl = &wlds[q * 32 * 64 + tu];          // gate 0 from LDS
        const float4* w1 = wbase + (long)(q * 32) * 1536 + (512 + ub + tu);
        const float4* w2 = w1 + 512;
#pragma unroll 8
        for (int k = 0; k < 32; k++) {
            float4 wv0 = wl[k * 64];
            float4 wv1 = w1[(long)k * 1536];
            float4 wv2 = w2[(long)k * 1536];
            float4 hv0 = h0v[k];
            float4 hv1 = h1v[k];
            a00 += wv0.x*hv0.x + wv0.y*hv0.y + wv0.z*hv0.z + wv0.w*hv0.w;
            a01 += wv0.x*hv1.x + wv0.y*hv1.y + wv0.z*hv1.z + wv0.w*hv1.w;
            a10 += wv1.x*hv0.x + wv1.y*hv0.y + wv1.z*hv0.z + wv1.w*hv0.w;
            a11 += wv1.x*hv1.x + wv1.y*hv1.y + wv1.z*hv1.z + wv1.w*hv1.w;
            a20 += wv2.x*hv0.x + wv2.y*hv0.y + wv2.z*hv0.z + wv2.w*hv0.w;
            a21 += wv2.x*hv1.x + wv2.y*hv1.y + wv2.z*hv1.z + wv2.w*hv1.w;
        }
        psum[q][0][0][tu] = a00;  psum[q][0][1][tu] = a01;
        psum[q][1][0][tu] = a10;  psum[q][1][1][tu] = a11;
        psum[q][2][0][tu] = a20;  psum[q][2][1][tu] = a21;
        __syncthreads();

        // ---- finalize on 128 threads ----
        if (tid < 128) {
            float sr = psum[0][0][fb][fu] + psum[1][0][fb][fu] + psum[2][0][fb][fu] + psum[3][0][fb][fu];
            float sz = psum[0][1][fb][fu] + psum[1][1][fb][fu] + psum[2][1][fb][fu] + psum[3][1][fb][fu];
            float sn = psum[0][2][fb][fu] + psum[1][2][fb][fu] + psum[2][2][fb][fu] + psum[3][2][fb][fu];
            const float* g = gi + ((long)sl * 64 + b0 + fb) * 1536;
            float ir = g[ub + fu], iz = g[512 + ub + fu], inn = g[1024 + ub + fu];
            float r  = 1.f / (1.f + expf(-(ir + sr + bhv0)));
            float zg = 1.f / (1.f + expf(-(iz + sz + bhv1)));
            float n  = tanhf(inn + r * (sn + bhv2));
            float hp = hl[fb][ub + fu];
            float hn = (1.f - zg) * n + zg * hp;
            u32 wt = (u32)(layer * 512 + s + 1);
            u64 pv = ((u64)wt << 32) | (u64)__float_as_uint(hn);
            u64* dst = hx + (u64)(wt & 1) * 32768 + ((long)p * 512 + ub + fu) * 2 + fb;
            __hip_atomic_exchange(dst, pv, __ATOMIC_RELAXED, __HIP_MEMORY_SCOPE_AGENT);
            seq_out[((long)s * 64 + b0 + fb) * 512 + ub + fu] = f2b(hn);
        }
        __syncthreads();
    }
}

// ---------------------------------------------------------------------------
__global__ __launch_bounds__(256) void final_kernel(
    const u16* __restrict__ h2, const float* __restrict__ Wf,
    const float* __restrict__ bfin, float* __restrict__ out)
{
    int w = blockIdx.x * 4 + (threadIdx.x >> 6);
    int lane = threadIdx.x & 63;
    const u16* row = h2 + (long)w * 512;
    uint4 hv = *(const uint4*)(row + lane * 8);
    float4 w0 = *(const float4*)(Wf + lane * 8);
    float4 w1 = *(const float4*)(Wf + lane * 8 + 4);
    float sum = b2f(hv.x & 0xffffu) * w0.x + b2fh(hv.x) * w0.y
              + b2f(hv.y & 0xffffu) * w0.z + b2fh(hv.y) * w0.w
              + b2f(hv.z & 0xffffu) * w1.x + b2fh(hv.z) * w1.y
              + b2f(hv.w & 0xffffu) * w1.z + b2fh(hv.w) * w1.w;
#pragma unroll
    for (int off = 32; off > 0; off >>= 1) sum += __shfl_down(sum, off, 64);
    if (lane == 0) {
        int s = w >> 6, b = w & 63;
        out[(long)b * 512 + s] = 1.f / (1.f + expf(-(sum + bfin[0])));
    }
}

// ---------------------------------------------------------------------------
// Launcher — workspace ~172.6 MB
// ---------------------------------------------------------------------------
extern "C" void kernel_launch(void* const* d_in, const int* in_sizes, int n_in,
                              void* d_out, int out_size, void* d_ws, size_t ws_size,
                              hipStream_t stream) {
    const int*   cate  = (const int*)  d_in[0];
    const float* cont  = (const float*)d_in[1];
    const float* emb   = (const float*)d_in[4];
    const float* Wc    = (const float*)d_in[5];
    const float* bc    = (const float*)d_in[6];
    const float* Wcomb = (const float*)d_in[7];
    const float* bcomb = (const float*)d_in[8];
    const float* Wq    = (const float*)d_in[9];
    const float* Wk    = (const float*)d_in[10];
    const float* Wv    = (const float*)d_in[11];
    const float* Wi    = (const float*)d_in[12];
    const float* Wh    = (const float*)d_in[13];
    const float* bi    = (const float*)d_in[14];
    const float* bh    = (const float*)d_in[15];
    const float* Wf    = (const float*)d_in[16];
    const float* bfin  = (const float*)d_in[17];
    float* out = (float*)d_out;
    char* ws = (char*)d_ws;

    u16*   zp    = (u16*)(ws + 0);
    u16*   h2bf  = (u16*)(ws + 0);
    u16*   h1bf  = (u16*)(ws + 33554432);
    float* gi    = (float*)(ws + 67108864);   // 50.3 MB, aliases xbf
    u16*   xbf   = (u16*)(ws + 67108864);
    u16*   QKV   = (u16*)(ws + 117440512);    // [4096][1536] bf16 = 12.58 MB
    u16*   Vt    = (u16*)(ws + 130023424);
    float* Sg    = (float*)(ws + 134217728);  // phase-2 only
    u64*   hx    = (u64*)  (ws + 134217728);  // 512 KB, aliases dead Sg (phase 3)
    u16*   Pg    = (u16*)(ws + 142606336);
    u16*   zT    = (u16*)(ws + 146800640);
    u16*   xc    = (u16*)(ws + 150994944);
    u16*   WcombT= (u16*)(ws + 159383552);
    u16*   WqT   = (u16*)(ws + 160432128);    // contiguous: WqT|WkT|WvT = [1536][512]
    u16*   WkT   = (u16*)(ws + 160956416);
    u16*   WvT   = (u16*)(ws + 161480704);
    u16*   WiB   = (u16*)(ws + 162004992);
    float* pe    = (float*)(ws + 165150720);
    float* WT4   = (float*)(ws + 166199296);  // [2][128][1536][4] fp32, 6.3 MB

    transp_w<<<dim3(16, 8), 256, 0, stream>>>(Wcomb, WcombT, 1024, 512);
    transp_w<<<dim3(8, 8),  256, 0, stream>>>(Wq, WqT, 512, 512);
    transp_w<<<dim3(8, 8),  256, 0, stream>>>(Wk, WkT, 512, 512);
    transp_w<<<dim3(8, 8),  256, 0, stream>>>(Wv, WvT, 512, 512);
    cvt_bf16<<<6144, 256, 0, stream>>>(Wi, WiB, 2L * 1536 * 512);
    wh_transp<<<6144, 256, 0, stream>>>(Wh, WT4);
    pe_kernel<<<512, 256, 0, stream>>>(pe);

    // phase 1
    for (int g = 0; g < 8; g++) {
        embed_kernel<<<4096, 256, 0, stream>>>(cate, cont, emb, Wc, bc, xc, g * 4096);
        gemm_nt<<<dim3(4, 32, 1), 256, 0, stream>>>(
            xc, WcombT, xbf + (long)g * 4096 * 512, 1024, 1024, 1024, 512,
            0, 0, 0, bcomb, pe, 1.f, 1);
    }

    // phase 2 (QKV fused: one N=1536 GEMM per group)
    for (int g = 0; g < 8; g++) {
        const u16* xg = xbf + (long)g * 8 * 512 * 512;
        gemm_nt<<<dim3(12, 32, 1), 256, 0, stream>>>(xg, WqT, QKV, 512,
                                                     512, 512, 1536,
                                                     0, 0, 0, nullptr, nullptr, 1.f, 1);
        // Vt[b][d][s] from V (QKV cols 1024..1535, ld 1536)
        transp_b<<<dim3(8, 8, 8), 256, 0, stream>>>(QKV + 1024, Vt, 512, 512, 1536,
                                                    (long)512 * 1536, 262144, 512);
        // S[b] = Q[b] @ K[b]^T / sqrt(A)
        gemm_nt<<<dim3(4, 4, 8), 256, 0, stream>>>(QKV, QKV + 512, Sg, 512,
                                                   1536, 1536, 512,
                                                   (long)512 * 1536, (long)512 * 1536, 262144,
                                                   nullptr, nullptr,
                                                   0.04419417382415922f, 0);
        softmax_q<<<dim3(8, 8), 64, 0, stream>>>(Sg, Pg);
        // zT[b] = Vt[b] @ P[b]^T
        gemm_nt<<<dim3(4, 4, 8), 256, 0, stream>>>(Vt, Pg, zT, 512, 512, 512, 512,
                                                   262144, 262144, 262144, nullptr, nullptr,
                                                   1.f, 1);
        transp_b<<<dim3(8, 8, 8), 256, 0, stream>>>(zT, zp + (long)g * 8 * 512,
                                                    512, 512, 512, 262144, 512, 32768);
    }

    // phase 3: GRU — unit-split cooperative (LDS gate-0 cache + load-gather)
    zero_kernel<<<1024, 256, 0, stream>>>((float*)hx, 262144);
    for (int l = 0; l < 2; l++) {
        const u16* Aseq = (l == 0) ? zp : h1bf;
        u16* seqOut = (l == 0) ? h1bf : h2bf;
        const u16* WiL = WiB + (long)l * 1536 * 512;
        const float* WT4L = WT4 + (long)l * 786432;
        const float* biL = bi + (long)l * 1536;
        const float* bhL = bh + (long)l * 1536;
        for (int seg = 0; seg < 4; seg++) {
            gemm_nt<<<dim3(12, 64, 1), 256, 0, stream>>>(
                Aseq + (long)seg * 128 * 64 * 512, WiL, gi, 512, 512, 512, 1536,
                0, 0, 0, biL, nullptr, 1.f, 0);
            const float* giP = gi;
            u16* soP = seqOut;
            int s0v = seg * 128;
            int lv = l;
            void* args[] = { (void*)&giP, (void*)&WT4L, (void*)&bhL, (void*)&soP,
                             (void*)&hx, (void*)&s0v, (void*)&lv };
            hipLaunchCooperativeKernel((void*)gru_ex, dim3(256), dim3(256),
                                       args, 0, stream);
        }
    }

    final_kernel<<<8192, 256, 0, stream>>>(h2bf, Wf, bfin, out);
}

// Round 15
// 7277.194 us; speedup vs baseline: 2.5388x; 1.1482x over previous
//
#include <hip/hip_runtime.h>
#include <hip/hip_bf16.h>
#include <math.h>

typedef unsigned short u16;
typedef unsigned int   u32;
typedef unsigned long long u64;
typedef __attribute__((ext_vector_type(8))) short short8;
typedef __attribute__((ext_vector_type(4))) float float4v;

#define BB 64
#define SS 512

// bf16 helpers (RNE)
__device__ __forceinline__ u16 f2b(float f) {
    u32 x = __float_as_uint(f);
    u32 r = (x + 0x7fffu + ((x >> 16) & 1u)) >> 16;
    return (u16)r;
}
__device__ __forceinline__ float b2f(u32 lo16) { return __uint_as_float(lo16 << 16); }
__device__ __forceinline__ float b2fh(u32 v)   { return __uint_as_float(v & 0xffff0000u); }

// ---------------------------------------------------------------------------
__global__ __launch_bounds__(256) void zero_kernel(float* __restrict__ p, int n) {
    int i = blockIdx.x * 256 + threadIdx.x;
    if (i < n) p[i] = 0.f;
}

// ---------------------------------------------------------------------------
__global__ __launch_bounds__(256) void pe_kernel(float* __restrict__ pe) {
    int s = blockIdx.x, j = threadIdx.x;
    float ang = (float)s * powf(10000.0f, -(2.0f * (float)j) / 512.0f);
    pe[s * 512 + 2 * j]     = sinf(ang);
    pe[s * 512 + 2 * j + 1] = cosf(ang);
}

// ---------------------------------------------------------------------------
// fp32 [R][C] -> bf16 [C][R]
// ---------------------------------------------------------------------------
__global__ __launch_bounds__(256) void transp_w(const float* __restrict__ in,
                                                u16* __restrict__ out, int R, int C) {
    __shared__ float t[64][65];
    int r0 = blockIdx.x * 64, c0 = blockIdx.y * 64;
    int tid = threadIdx.x;
    int lr = tid >> 4, lc4 = (tid & 15) * 4;
#pragma unroll
    for (int i = 0; i < 4; i++) {
        int r = lr + i * 16;
        float4 v = *(const float4*)(in + (long)(r0 + r) * C + c0 + lc4);
        t[r][lc4] = v.x; t[r][lc4 + 1] = v.y; t[r][lc4 + 2] = v.z; t[r][lc4 + 3] = v.w;
    }
    __syncthreads();
#pragma unroll
    for (int i = 0; i < 4; i++) {
        int c = lr + i * 16;
        u32 lo = (u32)f2b(t[lc4][c])     | ((u32)f2b(t[lc4 + 1][c]) << 16);
        u32 hi = (u32)f2b(t[lc4 + 2][c]) | ((u32)f2b(t[lc4 + 3][c]) << 16);
        uint2 pk; pk.x = lo; pk.y = hi;
        *(uint2*)(out + (long)(c0 + c) * R + r0 + lc4) = pk;
    }
}

// ---------------------------------------------------------------------------
__global__ __launch_bounds__(256) void cvt_bf16(const float* __restrict__ in,
                                                u16* __restrict__ out, long n) {
    long i = (long)blockIdx.x * 256 + threadIdx.x;
    if (i < n) out[i] = f2b(in[i]);
}

// ---------------------------------------------------------------------------
// Wh [2][1536][512] fp32 -> WT4 [2][128][1536][4] fp32  (k-blocked transpose)
// ---------------------------------------------------------------------------
__global__ __launch_bounds__(256) void wh_transp(const float* __restrict__ Wh,
                                                 float* __restrict__ WT4) {
    long i = (long)blockIdx.x * 256 + threadIdx.x;    // < 2*786432
    if (i >= 2L * 786432) return;
    long l = i / 786432;
    long r = i % 786432;
    int k4 = (int)(r / 6144);
    int rem = (int)(r % 6144);
    int j = rem >> 2, kk = rem & 3;
    WT4[i] = Wh[l * 786432 + (long)j * 512 + k4 * 4 + kk];
}

// ---------------------------------------------------------------------------
// bf16 [nb][R][C(ldin)] -> out[b][c][r] with element strides
// ---------------------------------------------------------------------------
__global__ __launch_bounds__(256) void transp_b(const u16* __restrict__ in,
                                                u16* __restrict__ out,
                                                int R, int C, int ldin,
                                                long sbin, long sb, long sc) {
    __shared__ u32 t[64][65];
    int bz = blockIdx.z;
    in += (long)bz * sbin;
    int r0 = blockIdx.x * 64, c0 = blockIdx.y * 64;
    int tid = threadIdx.x;
    int lr = tid >> 4, lc4 = (tid & 15) * 4;
#pragma unroll
    for (int i = 0; i < 4; i++) {
        int r = lr + i * 16;
        uint2 v = *(const uint2*)(in + (long)(r0 + r) * ldin + c0 + lc4);
        t[r][lc4] = v.x & 0xffffu; t[r][lc4 + 1] = v.x >> 16;
        t[r][lc4 + 2] = v.y & 0xffffu; t[r][lc4 + 3] = v.y >> 16;
    }
    __syncthreads();
#pragma unroll
    for (int i = 0; i < 4; i++) {
        int c = lr + i * 16;
        uint2 pk;
        pk.x = t[lc4][c] | (t[lc4 + 1][c] << 16);
        pk.y = t[lc4 + 2][c] | (t[lc4 + 3][c] << 16);
        *(uint2*)(out + (long)bz * sb + (long)(c0 + c) * sc + r0 + lc4) = pk;
    }
}

// ---------------------------------------------------------------------------
__global__ __launch_bounds__(256) void embed_kernel(
    const int* __restrict__ cate, const float* __restrict__ cont,
    const float* __restrict__ emb, const float* __restrict__ Wc,
    const float* __restrict__ bc, u16* __restrict__ xc, int gbase)
{
    long bs = (long)gbase + blockIdx.x;
    long r  = blockIdx.x;
    __shared__ float cf[6];
    if (threadIdx.x < 6) cf[threadIdx.x] = cont[bs * 6 + threadIdx.x];
    __syncthreads();
    for (int h = threadIdx.x; h < 1024; h += 256) {
        float v;
        if (h < 512) {
            int c = h >> 7, e = h & 127;
            int idx = cate[bs * 4 + c];
            v = emb[((long)c * 1000 + idx) * 128 + e];
        } else {
            int hh = h - 512;
            v = bc[hh];
#pragma unroll
            for (int f = 0; f < 6; f++) v += cf[f] * Wc[f * 512 + hh];
        }
        xc[r * 1024 + h] = f2b(v);
    }
}

// ---------------------------------------------------------------------------
// bf16 MFMA NT GEMM (validated: absmax 0.0)
// ---------------------------------------------------------------------------
__global__ __launch_bounds__(256) void gemm_nt(
    const u16* __restrict__ A, const u16* __restrict__ B, void* __restrict__ Cv,
    int K, int lda, int ldb, int ldc,
    long sA, long sB, long sC,
    const float* __restrict__ bias, const float* __restrict__ pe,
    float alpha, int outBf16)
{
    __shared__ u16 As[128][40];
    __shared__ u16 Bs[128][40];

    A += (long)blockIdx.z * sA;
    B += (long)blockIdx.z * sB;
    int m0 = blockIdx.y * 128, n0 = blockIdx.x * 128;
    int tid = threadIdx.x;
    int lane = tid & 63, wid = tid >> 6;
    int wm = (wid >> 1) * 64, wn = (wid & 1) * 64;
    int mrow = lane & 15, q8 = (lane >> 4) * 8;

    float4v acc[4][4];
#pragma unroll
    for (int i = 0; i < 4; i++)
#pragma unroll
        for (int j = 0; j < 4; j++) { float4v z = {0.f, 0.f, 0.f, 0.f}; acc[i][j] = z; }

    for (int k0 = 0; k0 < K; k0 += 32) {
        {
            int r = tid >> 2, sg = tid & 3;
            *(short8*)&As[r][sg * 8] = *(const short8*)(A + (long)(m0 + r) * lda + k0 + sg * 8);
            *(short8*)&Bs[r][sg * 8] = *(const short8*)(B + (long)(n0 + r) * ldb + k0 + sg * 8);
            r = (tid + 256) >> 2;
            *(short8*)&As[r][sg * 8] = *(const short8*)(A + (long)(m0 + r) * lda + k0 + sg * 8);
            *(short8*)&Bs[r][sg * 8] = *(const short8*)(B + (long)(n0 + r) * ldb + k0 + sg * 8);
        }
        __syncthreads();
        short8 af[4], bfr[4];
#pragma unroll
        for (int t = 0; t < 4; t++) {
            af[t]  = *(const short8*)&As[wm + t * 16 + mrow][q8];
            bfr[t] = *(const short8*)&Bs[wn + t * 16 + mrow][q8];
        }
#pragma unroll
        for (int i = 0; i < 4; i++)
#pragma unroll
            for (int j = 0; j < 4; j++)
                acc[i][j] = __builtin_amdgcn_mfma_f32_16x16x32_bf16(af[i], bfr[j], acc[i][j], 0, 0, 0);
        __syncthreads();
    }

    int col = lane & 15, quad = lane >> 4;
    u16*  Cb = (u16*)Cv  + (outBf16 ? (long)blockIdx.z * sC : 0);
    float* Cf = (float*)Cv + (outBf16 ? 0 : (long)blockIdx.z * sC);
#pragma unroll
    for (int i = 0; i < 4; i++)
#pragma unroll
        for (int j = 0; j < 4; j++) {
#pragma unroll
            for (int rr = 0; rr < 4; rr++) {
                int gm = m0 + wm + i * 16 + quad * 4 + rr;
                int gn = n0 + wn + j * 16 + col;
                float v = acc[i][j][rr] * alpha;
                if (bias) v += bias[gn];
                if (pe)   v += pe[(long)(gm & 511) * 512 + gn];
                if (outBf16) Cb[(long)gm * ldc + gn] = f2b(v);
                else         Cf[(long)gm * ldc + gn] = v;
            }
        }
}

// ---------------------------------------------------------------------------
// Softmax over QUERY axis fp32 -> bf16
// ---------------------------------------------------------------------------
__global__ __launch_bounds__(64) void softmax_q(const float* __restrict__ S,
                                                u16* __restrict__ P) {
    int b = blockIdx.x;
    int k = blockIdx.y * 64 + threadIdx.x;
    const float* p = S + (long)b * 262144 + k;
    u16* o = P + (long)b * 262144 + k;
    float m = -1e30f;
    for (int q = 0; q < 512; q++) m = fmaxf(m, p[(long)q * 512]);
    float sum = 0.f;
    for (int q = 0; q < 512; q++) sum += expf(p[(long)q * 512] - m);
    float inv = 1.f / sum;
    for (int q = 0; q < 512; q++) o[(long)q * 512] = f2b(expf(p[(long)q * 512] - m) * inv);
}

// ---------------------------------------------------------------------------
// Unit-split cooperative GRU — R14 structure (passed, absmax 0.0) widened to
// 512 threads/block (8 waves/CU): thread = (unit tu, k-EIGHTH q8). Per-thread
// FMA halves; 8 waves hide the gates-1/2 L2 stream. gi loads prefetched at
// step start (independent of h) to overlap gather latency.
// Gate-0 weights LDS-cached (128KB); gather = relaxed agent atomic loads;
// writes = atomic exchange. LDS total 147456 B -> 1 block/CU, 256 blocks.
// Weight register-hoisting remains BANNED (R9/R10/R12: 3/3 numeric fails).
// ---------------------------------------------------------------------------
__global__ __launch_bounds__(512, 1) void gru_ex(
    const float* __restrict__ gi,     // [128][64][1536] fp32 (includes bi)
    const float* __restrict__ WT4,    // [128 k4][1536 j][4 kk] fp32 (this layer)
    const float* __restrict__ bh_l,   // [1536]
    u16* __restrict__ seq_out,        // [512*64][512] bf16 (this layer)
    u64* __restrict__ hx,             // [2 parity][32 pair][512 unit][2 batch]
    int s0, int layer)
{
    __shared__ float hl[2][512];              // [batch-local][unit]        4 KB
    __shared__ float psum[8][3][2][64];       // [q8][gate][batch][unit]   12 KB
    __shared__ float4 wlds[8192];             // gate-0 slice [128k4][64u] 128 KB

    int blk = blockIdx.x;
    int p   = blk & 31;           // batch pair 0..31 (XCD-local remap)
    int sli = blk >> 5;           // unit slice 0..7
    int ub  = sli * 64;
    int tid = threadIdx.x;
    int tu  = tid & 63;           // unit within slice
    int q8  = tid >> 6;           // k-eighth 0..7 (16 k4 each)
    int b0  = p * 2;

    int fu = tid & 63, fb = (tid >> 6) & 1;   // finalize mapping (tid<128)
    float bhv0 = 0.f, bhv1 = 0.f, bhv2 = 0.f;
    if (tid < 128) {
        bhv0 = bh_l[ub + fu];
        bhv1 = bh_l[512 + ub + fu];
        bhv2 = bh_l[1024 + ub + fu];
    }

    const float4* wbase = (const float4*)WT4;

    // ---- fill gate-0 LDS cache once per segment (coalesced) ----
    for (int i = tid; i < 8192; i += 512) {
        int k4 = i >> 6, u = i & 63;
        wlds[i] = wbase[(long)k4 * 1536 + ub + u];
    }
    __syncthreads();

    for (int sl = 0; sl < 128; sl++) {
        int s = s0 + sl;

        // ---- prefetch gi for this step (independent of h exchange) ----
        float ir = 0.f, iz = 0.f, inn = 0.f;
        if (tid < 128) {
            const float* g = gi + ((long)sl * 64 + b0 + fb) * 1536;
            ir  = g[ub + fu];
            iz  = g[512 + ub + fu];
            inn = g[1024 + ub + fu];
        }

        // ---- gather h (or zero-init at layer start) ----
        if (s == 0) {
            for (int i = tid; i < 1024; i += 512) ((float*)hl)[i] = 0.f;
        } else {
            u32 exp_tag = (u32)(layer * 512 + s);
            u64* slot = hx + (u64)(exp_tag & 1) * 32768;
            int i0 = tid, i1 = tid + 512;
            u64* p0 = slot + ((long)p * 512 + (i0 >> 1)) * 2 + (i0 & 1);
            u64* p1 = slot + ((long)p * 512 + (i1 >> 1)) * 2 + (i1 & 1);
            int need = 0x3;
            while (need) {
                if (need & 1) {
                    u64 v = __hip_atomic_load(p0, __ATOMIC_RELAXED, __HIP_MEMORY_SCOPE_AGENT);
                    if ((u32)(v >> 32) == exp_tag) { hl[i0 & 1][i0 >> 1] = __uint_as_float((u32)v); need &= ~1; }
                }
                if (need & 2) {
                    u64 v = __hip_atomic_load(p1, __ATOMIC_RELAXED, __HIP_MEMORY_SCOPE_AGENT);
                    if ((u32)(v >> 32) == exp_tag) { hl[i1 & 1][i1 >> 1] = __uint_as_float((u32)v); need &= ~2; }
                }
                if (need) __builtin_amdgcn_s_sleep(1);
            }
        }
        __syncthreads();

        // ---- matvec partials: this thread = (unit tu, k-eighth q8) ----
        float a00 = 0.f, a01 = 0.f, a10 = 0.f, a11 = 0.f, a20 = 0.f, a21 = 0.f;
        const float4* h0v = (const float4*)hl[0] + q8 * 16;
        const float4* h1v = (const float4*)hl[1] + q8 * 16;
        const float4* wl = &wlds[q8 * 16 * 64 + tu];         // gate 0 from LDS
        const float4* w1 = wbase + (long)(q8 * 16) * 1536 + (512 + ub + tu);
        const float4* w2 = w1 + 512;
#pragma unroll 8
        for (int k = 0; k < 16; k++) {
            float4 wv0 = wl[k * 64];
            float4 wv1 = w1[(long)k * 1536];
            float4 wv2 = w2[(long)k * 1536];
            float4 hv0 = h0v[k];
            float4 hv1 = h1v[k];
            a00 += wv0.x*hv0.x + wv0.y*hv0.y + wv0.z*hv0.z + wv0.w*hv0.w;
            a01 += wv0.x*hv1.x + wv0.y*hv1.y + wv0.z*hv1.z + wv0.w*hv1.w;
            a10 += wv1.x*hv0.x + wv1.y*hv0.y + wv1.z*hv0.z + wv1.w*hv0.w;
            a11 += wv1.x*hv1.x + wv1.y*hv1.y + wv1.z*hv1.z + wv1.w*hv1.w;
            a20 += wv2.x*hv0.x + wv2.y*hv0.y + wv2.z*hv0.z + wv2.w*hv0.w;
            a21 += wv2.x*hv1.x + wv2.y*hv1.y + wv2.z*hv1.z + wv2.w*hv1.w;
        }
        psum[q8][0][0][tu] = a00;  psum[q8][0][1][tu] = a01;
        psum[q8][1][0][tu] = a10;  psum[q8][1][1][tu] = a11;
        psum[q8][2][0][tu] = a20;  psum[q8][2][1][tu] = a21;
        __syncthreads();

        // ---- finalize on 128 threads ----
        if (tid < 128) {
            float sr = 0.f, sz = 0.f, sn = 0.f;
#pragma unroll
            for (int qq = 0; qq < 8; qq++) {
                sr += psum[qq][0][fb][fu];
                sz += psum[qq][1][fb][fu];
                sn += psum[qq][2][fb][fu];
            }
            float r  = 1.f / (1.f + expf(-(ir + sr + bhv0)));
            float zg = 1.f / (1.f + expf(-(iz + sz + bhv1)));
            float n  = tanhf(inn + r * (sn + bhv2));
            float hp = hl[fb][ub + fu];
            float hn = (1.f - zg) * n + zg * hp;
            u32 wt = (u32)(layer * 512 + s + 1);
            u64 pv = ((u64)wt << 32) | (u64)__float_as_uint(hn);
            u64* dst = hx + (u64)(wt & 1) * 32768 + ((long)p * 512 + ub + fu) * 2 + fb;
            __hip_atomic_exchange(dst, pv, __ATOMIC_RELAXED, __HIP_MEMORY_SCOPE_AGENT);
            seq_out[((long)s * 64 + b0 + fb) * 512 + ub + fu] = f2b(hn);
        }
        __syncthreads();
    }
}

// ---------------------------------------------------------------------------
__global__ __launch_bounds__(256) void final_kernel(
    const u16* __restrict__ h2, const float* __restrict__ Wf,
    const float* __restrict__ bfin, float* __restrict__ out)
{
    int w = blockIdx.x * 4 + (threadIdx.x >> 6);
    int lane = threadIdx.x & 63;
    const u16* row = h2 + (long)w * 512;
    uint4 hv = *(const uint4*)(row + lane * 8);
    float4 w0 = *(const float4*)(Wf + lane * 8);
    float4 w1 = *(const float4*)(Wf + lane * 8 + 4);
    float sum = b2f(hv.x & 0xffffu) * w0.x + b2fh(hv.x) * w0.y
              + b2f(hv.y & 0xffffu) * w0.z + b2fh(hv.y) * w0.w
              + b2f(hv.z & 0xffffu) * w1.x + b2fh(hv.z) * w1.y
              + b2f(hv.w & 0xffffu) * w1.z + b2fh(hv.w) * w1.w;
#pragma unroll
    for (int off = 32; off > 0; off >>= 1) sum += __shfl_down(sum, off, 64);
    if (lane == 0) {
        int s = w >> 6, b = w & 63;
        out[(long)b * 512 + s] = 1.f / (1.f + expf(-(sum + bfin[0])));
    }
}

// ---------------------------------------------------------------------------
// Launcher — workspace ~172.6 MB
// ---------------------------------------------------------------------------
extern "C" void kernel_launch(void* const* d_in, const int* in_sizes, int n_in,
                              void* d_out, int out_size, void* d_ws, size_t ws_size,
                              hipStream_t stream) {
    const int*   cate  = (const int*)  d_in[0];
    const float* cont  = (const float*)d_in[1];
    const float* emb   = (const float*)d_in[4];
    const float* Wc    = (const float*)d_in[5];
    const float* bc    = (const float*)d_in[6];
    const float* Wcomb = (const float*)d_in[7];
    const float* bcomb = (const float*)d_in[8];
    const float* Wq    = (const float*)d_in[9];
    const float* Wk    = (const float*)d_in[10];
    const float* Wv    = (const float*)d_in[11];
    const float* Wi    = (const float*)d_in[12];
    const float* Wh    = (const float*)d_in[13];
    const float* bi    = (const float*)d_in[14];
    const float* bh    = (const float*)d_in[15];
    const float* Wf    = (const float*)d_in[16];
    const float* bfin  = (const float*)d_in[17];
    float* out = (float*)d_out;
    char* ws = (char*)d_ws;

    u16*   zp    = (u16*)(ws + 0);
    u16*   h2bf  = (u16*)(ws + 0);
    u16*   h1bf  = (u16*)(ws + 33554432);
    float* gi    = (float*)(ws + 67108864);   // 50.3 MB, aliases xbf
    u16*   xbf   = (u16*)(ws + 67108864);
    u16*   QKV   = (u16*)(ws + 117440512);    // [4096][1536] bf16 = 12.58 MB
    u16*   Vt    = (u16*)(ws + 130023424);
    float* Sg    = (float*)(ws + 134217728);  // phase-2 only
    u64*   hx    = (u64*)  (ws + 134217728);  // 512 KB, aliases dead Sg (phase 3)
    u16*   Pg    = (u16*)(ws + 142606336);
    u16*   zT    = (u16*)(ws + 146800640);
    u16*   xc    = (u16*)(ws + 150994944);
    u16*   WcombT= (u16*)(ws + 159383552);
    u16*   WqT   = (u16*)(ws + 160432128);    // contiguous: WqT|WkT|WvT = [1536][512]
    u16*   WkT   = (u16*)(ws + 160956416);
    u16*   WvT   = (u16*)(ws + 161480704);
    u16*   WiB   = (u16*)(ws + 162004992);
    float* pe    = (float*)(ws + 165150720);
    float* WT4   = (float*)(ws + 166199296);  // [2][128][1536][4] fp32, 6.3 MB

    transp_w<<<dim3(16, 8), 256, 0, stream>>>(Wcomb, WcombT, 1024, 512);
    transp_w<<<dim3(8, 8),  256, 0, stream>>>(Wq, WqT, 512, 512);
    transp_w<<<dim3(8, 8),  256, 0, stream>>>(Wk, WkT, 512, 512);
    transp_w<<<dim3(8, 8),  256, 0, stream>>>(Wv, WvT, 512, 512);
    cvt_bf16<<<6144, 256, 0, stream>>>(Wi, WiB, 2L * 1536 * 512);
    wh_transp<<<6144, 256, 0, stream>>>(Wh, WT4);
    pe_kernel<<<512, 256, 0, stream>>>(pe);

    // phase 1
    for (int g = 0; g < 8; g++) {
        embed_kernel<<<4096, 256, 0, stream>>>(cate, cont, emb, Wc, bc, xc, g * 4096);
        gemm_nt<<<dim3(4, 32, 1), 256, 0, stream>>>(
            xc, WcombT, xbf + (long)g * 4096 * 512, 1024, 1024, 1024, 512,
            0, 0, 0, bcomb, pe, 1.f, 1);
    }

    // phase 2 (QKV fused: one N=1536 GEMM per group)
    for (int g = 0; g < 8; g++) {
        const u16* xg = xbf + (long)g * 8 * 512 * 512;
        gemm_nt<<<dim3(12, 32, 1), 256, 0, stream>>>(xg, WqT, QKV, 512,
                                                     512, 512, 1536,
                                                     0, 0, 0, nullptr, nullptr, 1.f, 1);
        // Vt[b][d][s] from V (QKV cols 1024..1535, ld 1536)
        transp_b<<<dim3(8, 8, 8), 256, 0, stream>>>(QKV + 1024, Vt, 512, 512, 1536,
                                                    (long)512 * 1536, 262144, 512);
        // S[b] = Q[b] @ K[b]^T / sqrt(A)
        gemm_nt<<<dim3(4, 4, 8), 256, 0, stream>>>(QKV, QKV + 512, Sg, 512,
                                                   1536, 1536, 512,
                                                   (long)512 * 1536, (long)512 * 1536, 262144,
                                                   nullptr, nullptr,
                                                   0.04419417382415922f, 0);
        softmax_q<<<dim3(8, 8), 64, 0, stream>>>(Sg, Pg);
        // zT[b] = Vt[b] @ P[b]^T
        gemm_nt<<<dim3(4, 4, 8), 256, 0, stream>>>(Vt, Pg, zT, 512, 512, 512, 512,
                                                   262144, 262144, 262144, nullptr, nullptr,
                                                   1.f, 1);
        transp_b<<<dim3(8, 8, 8), 256, 0, stream>>>(zT, zp + (long)g * 8 * 512,
                                                    512, 512, 512, 262144, 512, 32768);
    }

    // phase 3: GRU — 512-thread unit-split cooperative
    zero_kernel<<<1024, 256, 0, stream>>>((float*)hx, 262144);
    for (int l = 0; l < 2; l++) {
        const u16* Aseq = (l == 0) ? zp : h1bf;
        u16* seqOut = (l == 0) ? h1bf : h2bf;
        const u16* WiL = WiB + (long)l * 1536 * 512;
        const float* WT4L = WT4 + (long)l * 786432;
        const float* biL = bi + (long)l * 1536;
        const float* bhL = bh + (long)l * 1536;
        for (int seg = 0; seg < 4; seg++) {
            gemm_nt<<<dim3(12, 64, 1), 256, 0, stream>>>(
                Aseq + (long)seg * 128 * 64 * 512, WiL, gi, 512, 512, 512, 1536,
                0, 0, 0, biL, nullptr, 1.f, 0);
            const float* giP = gi;
            u16* soP = seqOut;
            int s0v = seg * 128;
            int lv = l;
            void* args[] = { (void*)&giP, (void*)&WT4L, (void*)&bhL, (void*)&soP,
                             (void*)&hx, (void*)&s0v, (void*)&lv };
            hipLaunchCooperativeKernel((void*)gru_ex, dim3(256), dim3(512),
                                       args, 0, stream);
        }
    }

    final_kernel<<<8192, 256, 0, stream>>>(h2bf, Wf, bfin, out);
}